// Round 3
// baseline (1078.462 us; speedup 1.0000x reference)
//
#include <hip/hip_runtime.h>

#define B_   16
#define CIN  128
#define NPT  2048
#define COUT 256
#define KNN  20
#define EPS  1e-5f

// workspace byte offsets
#define SQ_OFF   0ull                          // sqh: 32768 f (fp16-rounded |x|^2)
#define IDX_OFF  131072ull                     // 16*2048*20 i32
#define UT_OFF   2752512ull                    // 16*2048*256 f
#define VT_OFF   36306944ull                   // 16*2048*256 f
#define GS_OFF   69861376ull                   // 2*256 double
#define ST_OFF   69865472ull                   // 2*256 f
// xT[b][n][c] fp32 (16.8 MB) aliases uT; xhT[b][n][c] fp16 (8.4 MB) aliases vT.
// prep writes both; knn reads them; uv_gemm (runs after knn) overwrites.
#define XT_OFF   UT_OFF
#define XHT_OFF  VT_OFF

typedef _Float16 f16x8 __attribute__((ext_vector_type(8)));
typedef float    f32x4 __attribute__((ext_vector_type(4)));

// ---------------------------------------------------- prep: xT, xhT, sqh
// Per block: 64 n x 128 c tile. Produces fp32 transpose (for fp64 refine),
// fp16 transpose (MFMA operands), and sqh[n] = sum_c (fp16(x))^2.
__global__ __launch_bounds__(256) void prep_kernel(const float* __restrict__ x,
                                                   float* __restrict__ xT,
                                                   _Float16* __restrict__ xhT,
                                                   float* __restrict__ sqh) {
    __shared__ float Ls[128 * 68];
    __shared__ float ps[4 * 64];
    const int b = blockIdx.y, n0 = blockIdx.x * 64, t = threadIdx.x;
    const float* xb = x + (size_t)b * CIN * NPT;
    #pragma unroll
    for (int e = 0; e < 8; ++e) {              // 2048 float4 loads, coalesced
        int f = e * 256 + t;
        int c = f >> 4, n4 = (f & 15) << 2;
        *(float4*)&Ls[c * 68 + n4] = *(const float4*)&xb[(size_t)c * NPT + n0 + n4];
    }
    __syncthreads();
    {                                          // sq partials on fp16-rounded vals
        int nl = t & 63, part = t >> 6;
        float acc = 0.f;
        #pragma unroll
        for (int j = 0; j < 32; ++j) {
            float vh = (float)(_Float16)Ls[(part * 32 + j) * 68 + nl];
            acc += vh * vh;
        }
        ps[part * 64 + nl] = acc;
    }
    #pragma unroll
    for (int e = 0; e < 2; ++e) {              // transpose writes: (nl, 16-c chunk)
        int u = e * 256 + t;
        int nl = u >> 3, ck = (u & 7) << 4;
        float vv[16];
        #pragma unroll
        for (int j = 0; j < 16; ++j) vv[j] = Ls[(ck + j) * 68 + nl];
        size_t row = (size_t)b * NPT + n0 + nl;
        #pragma unroll
        for (int j = 0; j < 4; ++j) {
            float4 w = {vv[4 * j], vv[4 * j + 1], vv[4 * j + 2], vv[4 * j + 3]};
            *(float4*)&xT[row * CIN + ck + 4 * j] = w;
        }
        f16x8 h0, h1;
        #pragma unroll
        for (int j = 0; j < 8; ++j) { h0[j] = (_Float16)vv[j]; h1[j] = (_Float16)vv[8 + j]; }
        *(f16x8*)&xhT[row * CIN + ck] = h0;
        *(f16x8*)&xhT[row * CIN + ck + 8] = h1;
    }
    __syncthreads();
    if (t < 64) sqh[b * NPT + n0 + t] = ps[t] + ps[64 + t] + ps[128 + t] + ps[192 + t];
}

// -------------------------------------------- fragment staging via DMA
// 1024 slots of 16B in MFMA fragment order: slot((pt16,ks,lane)) holds
// xh[base_n + pt16*16 + (lane&15)][ks*32 + (lane>>4)*8 .. +8].
__device__ __forceinline__ void stage_pts(const _Float16* __restrict__ xhb,
                                          _Float16* buf, int base_n, int t) {
    const int l15 = t & 15, quad = (t >> 4) & 3, ks = t >> 6;
    const int c = ks * 32 + quad * 8;
    #pragma unroll
    for (int e = 0; e < 4; ++e) {
        const int n = base_n + e * 16 + l15;
        const _Float16* src = xhb + (size_t)n * CIN + c;
        _Float16* dst = buf + (size_t)(e * 256 + (t & 192)) * 8;   // wave-uniform base
        __builtin_amdgcn_global_load_lds(
            (const __attribute__((address_space(1))) void*)src,
            (__attribute__((address_space(3))) void*)dst, 16, 0, 0);
    }
}

// ---------------------------------------------------------------- KNN
// fp16 MFMA distance tiles (64q x 2048m per block) + per-lane top-20 over 4
// disjoint m-subsets + fp64 refinement of 80 candidates -> exact top-20 set.
__global__ __launch_bounds__(256, 2) void knn_kernel(const _Float16* __restrict__ xhT,
                                                     const float* __restrict__ xT,
                                                     const float* __restrict__ sqh,
                                                     int* __restrict__ knn_out) {
    __shared__ char smraw[58368];
    _Float16* bufA = (_Float16*)smraw;              // 16 KB: A frags, then B dbuf
    _Float16* bufB = (_Float16*)(smraw + 16384);    // 16 KB: B frags
    float*    Dt   = (float*)(smraw + 32768);       // 64 x 68 f
    float*    sqm  = (float*)(smraw + 50176);       // 2048 f

    const int b  = blockIdx.y;
    const int q0 = blockIdx.x * 64;
    const int t  = threadIdx.x;
    const int lane = t & 63, wv = t >> 6;
    const int l15 = lane & 15, quad = lane >> 4;
    const _Float16* xhb = xhT + (size_t)b * NPT * CIN;

    #pragma unroll
    for (int e = 0; e < 8; ++e) sqm[e * 256 + t] = sqh[b * NPT + e * 256 + t];

    stage_pts(xhb, bufA, q0, t);                    // A fragments (64 queries)
    __syncthreads();
    f16x8 af[4];
    #pragma unroll
    for (int ks = 0; ks < 4; ++ks)
        af[ks] = *(const f16x8*)(bufA + (size_t)((wv * 4 + ks) * 64 + lane) * 8);
    stage_pts(xhb, bufB, 0, t);                     // B stage 0

    float bd[KNN]; int bi[KNN];
    #pragma unroll
    for (int i = 0; i < KNN; ++i) { bd[i] = 3e38f; bi[i] = 0; }
    const int qi = t >> 2, r = t & 3;

    #pragma unroll 1
    for (int s = 0; s < 32; ++s) {
        __syncthreads();                            // buf[s&1] ready; Dt consumed
        _Float16* cur = (s & 1) ? bufA : bufB;
        if (s < 31) stage_pts(xhb, (s & 1) ? bufB : bufA, (s + 1) * 64, t);
        const int m0 = s * 64;
        f32x4 acc[4];
        #pragma unroll
        for (int mt4 = 0; mt4 < 4; ++mt4) acc[mt4] = (f32x4){0.f, 0.f, 0.f, 0.f};
        #pragma unroll
        for (int ks = 0; ks < 4; ++ks) {
            #pragma unroll
            for (int mt4 = 0; mt4 < 4; ++mt4) {
                f16x8 bf = *(const f16x8*)(cur + (size_t)((mt4 * 4 + ks) * 64 + lane) * 8);
                acc[mt4] = __builtin_amdgcn_mfma_f32_16x16x32_f16(af[ks], bf, acc[mt4], 0, 0, 0);
            }
        }
        #pragma unroll
        for (int mt4 = 0; mt4 < 4; ++mt4) {
            float sm_ = sqm[m0 + mt4 * 16 + l15];
            #pragma unroll
            for (int reg = 0; reg < 4; ++reg) {     // D row = q (A free dim)
                int q = wv * 16 + quad * 4 + reg;
                Dt[q * 68 + mt4 * 16 + l15] = sm_ - 2.f * acc[mt4][reg];
            }
        }
        __syncthreads();                            // Dt(s) visible
        #pragma unroll 4
        for (int i2 = 0; i2 < 16; ++i2) {           // thread (qi,r): subset m%4==r
            int mi = (i2 << 2) + r;
            float d = Dt[qi * 68 + mi];
            if (d < bd[KNN - 1]) {
                bd[KNN - 1] = d; bi[KNN - 1] = m0 + mi;
                #pragma unroll
                for (int sj = KNN - 1; sj > 0; --sj) {
                    if (bd[sj] < bd[sj - 1]) {
                        float td = bd[sj]; bd[sj] = bd[sj - 1]; bd[sj - 1] = td;
                        int ti = bi[sj]; bi[sj] = bi[sj - 1]; bi[sj - 1] = ti;
                    }
                }
            }
        }
    }

    // ---- fp64 refinement from fp32 xT rows (exact vs numpy) ----
    double dd[KNN];
    #pragma unroll
    for (int i = 0; i < KNN; ++i) dd[i] = 0.0;
    const float* xTb = xT + (size_t)b * NPT * CIN;
    const float* qrow = xTb + (size_t)(q0 + qi) * CIN;
    #pragma unroll 1
    for (int ch = 0; ch < 8; ++ch) {
        double qd[16];
        #pragma unroll
        for (int j = 0; j < 4; ++j) {
            float4 qv = *(const float4*)&qrow[ch * 16 + 4 * j];
            qd[4 * j] = (double)qv.x; qd[4 * j + 1] = (double)qv.y;
            qd[4 * j + 2] = (double)qv.z; qd[4 * j + 3] = (double)qv.w;
        }
        #pragma unroll
        for (int i = 0; i < KNN; ++i) {
            const float* mrow = xTb + (size_t)bi[i] * CIN + ch * 16;
            float4 ma = *(const float4*)&mrow[0];
            float4 mb = *(const float4*)&mrow[4];
            float4 mc = *(const float4*)&mrow[8];
            float4 md = *(const float4*)&mrow[12];
            double ss = dd[i], d0;
            d0 = qd[0]  - (double)ma.x; ss = fma(d0, d0, ss);
            d0 = qd[1]  - (double)ma.y; ss = fma(d0, d0, ss);
            d0 = qd[2]  - (double)ma.z; ss = fma(d0, d0, ss);
            d0 = qd[3]  - (double)ma.w; ss = fma(d0, d0, ss);
            d0 = qd[4]  - (double)mb.x; ss = fma(d0, d0, ss);
            d0 = qd[5]  - (double)mb.y; ss = fma(d0, d0, ss);
            d0 = qd[6]  - (double)mb.z; ss = fma(d0, d0, ss);
            d0 = qd[7]  - (double)mb.w; ss = fma(d0, d0, ss);
            d0 = qd[8]  - (double)mc.x; ss = fma(d0, d0, ss);
            d0 = qd[9]  - (double)mc.y; ss = fma(d0, d0, ss);
            d0 = qd[10] - (double)mc.z; ss = fma(d0, d0, ss);
            d0 = qd[11] - (double)mc.w; ss = fma(d0, d0, ss);
            d0 = qd[12] - (double)md.x; ss = fma(d0, d0, ss);
            d0 = qd[13] - (double)md.y; ss = fma(d0, d0, ss);
            d0 = qd[14] - (double)md.z; ss = fma(d0, d0, ss);
            d0 = qd[15] - (double)md.w; ss = fma(d0, d0, ss);
            dd[i] = ss;
        }
    }

    // ---- exact selection over 80 candidates: 2 phases of 32 queries ----
    double* rD = (double*)smraw;                   // 32*80*8 = 20480 B
    int*    rI = (int*)(smraw + 20480);            // 32*80*4 = 10240 B
    #pragma unroll 1
    for (int ph = 0; ph < 2; ++ph) {
        __syncthreads();
        if ((qi >> 5) == ph) {
            const int lq = qi & 31;
            #pragma unroll
            for (int i = 0; i < KNN; ++i) {
                rD[lq * 80 + r * KNN + i] = dd[i];
                rI[lq * 80 + r * KNN + i] = bi[i];
            }
        }
        __syncthreads();
        if (t < 32) {
            const int n = q0 + ph * 32 + t;
            int* dst = knn_out + ((size_t)b * NPT + n) * KNN;
            double* Lq = rD + t * 80;
            const int* Li = rI + t * 80;
            #pragma unroll 1
            for (int o = 0; o < KNN; ++o) {
                double best = Lq[0]; int bp = 0;
                #pragma unroll 1
                for (int j2 = 1; j2 < 80; ++j2) {
                    double v = Lq[j2];
                    if (v < best) { best = v; bp = j2; }
                }
                dst[o] = Li[bp];
                Lq[bp] = 1e300;
            }
        }
    }
}

// ------------------------------------------------- u/v GEMM: uT/vT[b][n][o]
__global__ __launch_bounds__(256) void uv_gemm(const float* __restrict__ x,
                                               const float* __restrict__ W,
                                               float* __restrict__ uT,
                                               float* __restrict__ vT) {
    __shared__ float Ax[32 * 64];
    __shared__ float Bu[32 * 68];
    __shared__ float Bv[32 * 68];

    const int b  = blockIdx.z;
    const int n0 = blockIdx.x * 64;
    const int o0 = blockIdx.y * 64;
    const int t  = threadIdx.x;
    const int tx = t & 15, ty = t >> 4;
    const float* xb = x + (size_t)b * CIN * NPT;

    float au[4][4], av_[4][4];
    #pragma unroll
    for (int i = 0; i < 4; ++i)
        #pragma unroll
        for (int j = 0; j < 4; ++j) { au[i][j] = 0.f; av_[i][j] = 0.f; }

    #pragma unroll 1
    for (int kc = 0; kc < 4; ++kc) {
        const int c0 = kc * 32;
        __syncthreads();
        #pragma unroll
        for (int e = 0; e < 2; ++e) {
            int f = e * 256 + t;
            int cz = f >> 4, ni = (f & 15) << 2;
            *(float4*)&Ax[(cz << 6) + ni] = *(const float4*)&xb[(size_t)(c0 + cz) * NPT + n0 + ni];
        }
        #pragma unroll
        for (int e = 0; e < 8; ++e) {
            int ii = e * 256 + t;
            int cz = ii & 31, oj = ii >> 5;
            float w1 = W[(size_t)(o0 + oj) * 256 + c0 + cz];
            float w2 = W[(size_t)(o0 + oj) * 256 + 128 + c0 + cz];
            Bu[cz * 68 + oj] = w1 - w2;
            Bv[cz * 68 + oj] = w2;
        }
        __syncthreads();
        #pragma unroll 8
        for (int cz = 0; cz < 32; ++cz) {
            const float4 a4 = *(const float4*)&Ax[(cz << 6) + (tx << 2)];
            float bu0 = Bu[cz * 68 + (ty << 2) + 0], bv0 = Bv[cz * 68 + (ty << 2) + 0];
            float bu1 = Bu[cz * 68 + (ty << 2) + 1], bv1 = Bv[cz * 68 + (ty << 2) + 1];
            float bu2 = Bu[cz * 68 + (ty << 2) + 2], bv2 = Bv[cz * 68 + (ty << 2) + 2];
            float bu3 = Bu[cz * 68 + (ty << 2) + 3], bv3 = Bv[cz * 68 + (ty << 2) + 3];
            au[0][0] += a4.x * bu0; au[0][1] += a4.x * bu1; au[0][2] += a4.x * bu2; au[0][3] += a4.x * bu3;
            au[1][0] += a4.y * bu0; au[1][1] += a4.y * bu1; au[1][2] += a4.y * bu2; au[1][3] += a4.y * bu3;
            au[2][0] += a4.z * bu0; au[2][1] += a4.z * bu1; au[2][2] += a4.z * bu2; au[2][3] += a4.z * bu3;
            au[3][0] += a4.w * bu0; au[3][1] += a4.w * bu1; au[3][2] += a4.w * bu2; au[3][3] += a4.w * bu3;
            av_[0][0] += a4.x * bv0; av_[0][1] += a4.x * bv1; av_[0][2] += a4.x * bv2; av_[0][3] += a4.x * bv3;
            av_[1][0] += a4.y * bv0; av_[1][1] += a4.y * bv1; av_[1][2] += a4.y * bv2; av_[1][3] += a4.y * bv3;
            av_[2][0] += a4.z * bv0; av_[2][1] += a4.z * bv1; av_[2][2] += a4.z * bv2; av_[2][3] += a4.z * bv3;
            av_[3][0] += a4.w * bv0; av_[3][1] += a4.w * bv1; av_[3][2] += a4.w * bv2; av_[3][3] += a4.w * bv3;
        }
    }
    #pragma unroll
    for (int i = 0; i < 4; ++i) {
        int n = n0 + (tx << 2) + i;
        size_t base = ((size_t)b * NPT + n) * COUT + o0 + (ty << 2);
        float4 u4 = {au[i][0], au[i][1], au[i][2], au[i][3]};
        float4 v4 = {av_[i][0], av_[i][1], av_[i][2], av_[i][3]};
        *(float4*)&uT[base] = u4;
        *(float4*)&vT[base] = v4;
    }
}

// ------------------------------------------------- BN statistics (pass A)
__global__ __launch_bounds__(256) void stats_kernel(const float* __restrict__ uT,
                                                    const float* __restrict__ vT,
                                                    const int* __restrict__ knn_in,
                                                    double* __restrict__ gsum) {
    __shared__ int sidx[64 * KNN];
    const int b  = blockIdx.y;
    const int n0 = blockIdx.x * 64;
    const int o  = threadIdx.x;
    for (int e = o; e < 64 * KNN; e += 256)
        sidx[e] = knn_in[((size_t)b * NPT + n0) * KNN + e];
    __syncthreads();
    const float* ub = uT + ((size_t)b * NPT + n0) * COUT + o;
    const float* vb = vT + (size_t)b * NPT * COUT + o;
    double s1 = 0.0, s2 = 0.0;
    #pragma unroll 1
    for (int s = 0; s < 64; ++s) {
        float u = ub[(size_t)s * COUT];
        #pragma unroll
        for (int j = 0; j < KNN; ++j) {
            float y = u + vb[(size_t)sidx[s * KNN + j] * COUT];
            s1 += (double)y;
            s2 = fma((double)y, (double)y, s2);
        }
    }
    atomicAdd(&gsum[o], s1);
    atomicAdd(&gsum[COUT + o], s2);
}

// ------------------------------------------------- fold stats -> scale/shift
__global__ void finalize_kernel(const double* __restrict__ gsum,
                                const float* __restrict__ gamma,
                                const float* __restrict__ beta,
                                float* __restrict__ st) {
    const int o = threadIdx.x;
    const double M = (double)B_ * NPT * KNN;
    double mean = gsum[o] / M;
    double var  = gsum[COUT + o] / M - mean * mean;
    float inv = 1.0f / sqrtf((float)var + EPS);
    float s = gamma[o] * inv;
    st[o] = s;
    st[COUT + o] = beta[o] - (float)mean * s;
}

// ------------------------------------------------- gather+affine+relu+max
__global__ __launch_bounds__(256, 2) void out_kernel(const float* __restrict__ uT,
                                                     const float* __restrict__ vT,
                                                     const int* __restrict__ knn_in,
                                                     const float* __restrict__ st,
                                                     float* __restrict__ out) {
    __shared__ int sidx[64 * KNN];
    __shared__ float zt[256 * 68];
    const int b  = blockIdx.y;
    const int n0 = blockIdx.x * 64;
    const int o  = threadIdx.x;
    for (int e = o; e < 64 * KNN; e += 256)
        sidx[e] = knn_in[((size_t)b * NPT + n0) * KNN + e];
    __syncthreads();
    const float s  = st[o];
    const float tt = st[COUT + o];
    const float* ub = uT + ((size_t)b * NPT + n0) * COUT + o;
    const float* vb = vT + (size_t)b * NPT * COUT + o;
    #pragma unroll 1
    for (int si = 0; si < 64; ++si) {
        float u = ub[(size_t)si * COUT];
        float ymax = -3e38f, ymin = 3e38f;
        #pragma unroll
        for (int j = 0; j < KNN; ++j) {
            float y = u + vb[(size_t)sidx[si * KNN + j] * COUT];
            ymax = fmaxf(ymax, y);
            ymin = fminf(ymin, y);
        }
        float z1 = fmaxf(s * ymax + tt, 0.f);
        float z2 = fmaxf(s * ymin + tt, 0.f);
        zt[o * 68 + si] = fmaxf(z1, z2);
    }
    __syncthreads();
    float* dst = out + ((size_t)b * COUT + o) * NPT + n0;
    #pragma unroll
    for (int i = 0; i < 16; ++i)
        *(float4*)&dst[i * 4] = *(const float4*)&zt[o * 68 + i * 4];
}

extern "C" void kernel_launch(void* const* d_in, const int* in_sizes, int n_in,
                              void* d_out, int out_size, void* d_ws, size_t ws_size,
                              hipStream_t stream) {
    const float* x     = (const float*)d_in[0];
    const float* W     = (const float*)d_in[1];
    const float* gamma = (const float*)d_in[2];
    const float* beta  = (const float*)d_in[3];
    float* out = (float*)d_out;
    char* ws = (char*)d_ws;
    float*     sqh  = (float*)(ws + SQ_OFF);
    int*       idx  = (int*)(ws + IDX_OFF);
    float*     xT   = (float*)(ws + XT_OFF);    // aliases uT
    _Float16*  xhT  = (_Float16*)(ws + XHT_OFF);// aliases vT
    float*     uT   = (float*)(ws + UT_OFF);
    float*     vT   = (float*)(ws + VT_OFF);
    double*    gsum = (double*)(ws + GS_OFF);
    float*     st   = (float*)(ws + ST_OFF);

    hipMemsetAsync(gsum, 0, 2 * COUT * sizeof(double), stream);
    prep_kernel<<<dim3(32, 16), 256, 0, stream>>>(x, xT, xhT, sqh);
    knn_kernel<<<dim3(32, 16), 256, 0, stream>>>(xhT, xT, sqh, idx);
    // uv_gemm AFTER knn: uT/vT regions alias xT/xhT
    uv_gemm<<<dim3(32, 4, 16), 256, 0, stream>>>(x, W, uT, vT);
    stats_kernel<<<dim3(32, 16), 256, 0, stream>>>(uT, vT, idx, gsum);
    finalize_kernel<<<1, 256, 0, stream>>>(gsum, gamma, beta, st);
    out_kernel<<<dim3(32, 16), 256, 0, stream>>>(uT, vT, idx, st, out);
}

// Round 5
// 711.053 us; speedup vs baseline: 1.5167x; 1.5167x over previous
//
#include <hip/hip_runtime.h>

#define B_   16
#define CIN  128
#define NPT  2048
#define COUT 256
#define KNN  20
#define KEEP 24
#define CAND 96
#define EPS  1e-5f
#define DBIAS 256.0f   // must exceed max_q |x_q|^2 (chi2_128 max ~210 over 32k)

// workspace byte offsets
#define SQ_OFF   0ull                          // sqh: 32768 f (fp16-rounded |x|^2)
#define IDX_OFF  131072ull                     // 16*2048*20 i32
#define UT_OFF   2752512ull                    // 16*2048*256 f
#define VT_OFF   36306944ull                   // 16*2048*256 f
#define GS_OFF   69861376ull                   // 2*256 double
#define ST_OFF   69865472ull                   // 2*256 f
// xT[b][n][c] fp32 (16.8 MB) aliases uT; xhT[b][n][c] fp16 (8.4 MB) aliases vT.
// prep writes both; knn reads them; uv_gemm (runs after knn) overwrites.
#define XT_OFF   UT_OFF
#define XHT_OFF  VT_OFF

typedef _Float16 f16x8 __attribute__((ext_vector_type(8)));
typedef float    f32x4 __attribute__((ext_vector_type(4)));

// ---------------------------------------------------- prep: xT, xhT, sqh
__global__ __launch_bounds__(256) void prep_kernel(const float* __restrict__ x,
                                                   float* __restrict__ xT,
                                                   _Float16* __restrict__ xhT,
                                                   float* __restrict__ sqh) {
    __shared__ float Ls[128 * 68];
    __shared__ float ps[4 * 64];
    const int b = blockIdx.y, n0 = blockIdx.x * 64, t = threadIdx.x;
    const float* xb = x + (size_t)b * CIN * NPT;
    #pragma unroll
    for (int e = 0; e < 8; ++e) {              // 2048 float4 loads, coalesced
        int f = e * 256 + t;
        int c = f >> 4, n4 = (f & 15) << 2;
        *(float4*)&Ls[c * 68 + n4] = *(const float4*)&xb[(size_t)c * NPT + n0 + n4];
    }
    __syncthreads();
    {                                          // sq partials on fp16-rounded vals
        int nl = t & 63, part = t >> 6;
        float acc = 0.f;
        #pragma unroll
        for (int j = 0; j < 32; ++j) {
            float vh = (float)(_Float16)Ls[(part * 32 + j) * 68 + nl];
            acc += vh * vh;
        }
        ps[part * 64 + nl] = acc;
    }
    #pragma unroll
    for (int e = 0; e < 2; ++e) {              // transpose writes: (nl, 16-c chunk)
        int u = e * 256 + t;
        int nl = u >> 3, ck = (u & 7) << 4;
        float vv[16];
        #pragma unroll
        for (int j = 0; j < 16; ++j) vv[j] = Ls[(ck + j) * 68 + nl];
        size_t row = (size_t)b * NPT + n0 + nl;
        #pragma unroll
        for (int j = 0; j < 4; ++j) {
            float4 w = {vv[4 * j], vv[4 * j + 1], vv[4 * j + 2], vv[4 * j + 3]};
            *(float4*)&xT[row * CIN + ck + 4 * j] = w;
        }
        f16x8 h0, h1;
        #pragma unroll
        for (int j = 0; j < 8; ++j) { h0[j] = (_Float16)vv[j]; h1[j] = (_Float16)vv[8 + j]; }
        *(f16x8*)&xhT[row * CIN + ck] = h0;
        *(f16x8*)&xhT[row * CIN + ck + 8] = h1;
    }
    __syncthreads();
    if (t < 64) sqh[b * NPT + n0 + t] = ps[t] + ps[64 + t] + ps[128 + t] + ps[192 + t];
}

// -------------------------------------------- fragment staging via DMA
__device__ __forceinline__ void stage_pts(const _Float16* __restrict__ xhb,
                                          _Float16* buf, int base_n, int t) {
    const int l15 = t & 15, ks = t >> 6;
    const int quad = (t >> 4) & 3;
    const int c = ks * 32 + quad * 8;
    #pragma unroll
    for (int e = 0; e < 4; ++e) {
        const int n = base_n + e * 16 + l15;
        const _Float16* src = xhb + (size_t)n * CIN + c;
        _Float16* dst = buf + (size_t)(e * 256 + (t & 192)) * 8;   // wave-uniform base
        __builtin_amdgcn_global_load_lds(
            (const __attribute__((address_space(1))) void*)src,
            (__attribute__((address_space(3))) void*)dst, 16, 0, 0);
    }
}

// ---------------------------------------------------------------- KNN
// fp16 MFMA distance tiles + per-lane top-24 via packed-u32 min/max chain
// (23-bit quantized POSITIVE key | 9-bit subset index) + fp64 refinement of
// 96 candidates -> exact top-20 set.
__global__ __launch_bounds__(256, 2) void knn_kernel(const _Float16* __restrict__ xhT,
                                                     const float* __restrict__ xT,
                                                     const float* __restrict__ sqh,
                                                     int* __restrict__ knn_out) {
    __shared__ char smraw[58368];
    _Float16* bufA = (_Float16*)smraw;              // 16 KB: A frags, then B dbuf
    _Float16* bufB = (_Float16*)(smraw + 16384);    // 16 KB: B frags
    float*    Dt   = (float*)(smraw + 32768);       // 64 x 68 f
    float*    sqm  = (float*)(smraw + 50176);       // 2048 f (biased +DBIAS)

    const int b  = blockIdx.y;
    const int q0 = blockIdx.x * 64;
    const int t  = threadIdx.x;
    const int lane = t & 63, wv = t >> 6;
    const int l15 = lane & 15, quad = lane >> 4;
    const _Float16* xhb = xhT + (size_t)b * NPT * CIN;

    // Dt[q][m] = |xm|^2 + DBIAS - 2<q,m>  (drops |xq|^2: constant per query).
    // DBIAS > max |xq|^2 keeps Dt > 0 so u32 bit order == value order.
    #pragma unroll
    for (int e = 0; e < 8; ++e)
        sqm[e * 256 + t] = sqh[b * NPT + e * 256 + t] + DBIAS;

    stage_pts(xhb, bufA, q0, t);                    // A fragments (64 queries)
    __syncthreads();
    f16x8 af[4];
    #pragma unroll
    for (int ks = 0; ks < 4; ++ks)
        af[ks] = *(const f16x8*)(bufA + (size_t)((wv * 4 + ks) * 64 + lane) * 8);
    stage_pts(xhb, bufB, 0, t);                     // B stage 0

    unsigned bd[KEEP];
    #pragma unroll
    for (int i = 0; i < KEEP; ++i) bd[i] = 0xFFFFFFFFu;
    const int qi = t >> 2, r = t & 3;

    #pragma unroll 1
    for (int s = 0; s < 32; ++s) {
        __syncthreads();                            // buf[s&1] ready; Dt consumed
        _Float16* cur = (s & 1) ? bufA : bufB;
        if (s < 31) stage_pts(xhb, (s & 1) ? bufB : bufA, (s + 1) * 64, t);
        const int m0 = s * 64;
        f32x4 acc[4];
        #pragma unroll
        for (int mt4 = 0; mt4 < 4; ++mt4) acc[mt4] = (f32x4){0.f, 0.f, 0.f, 0.f};
        #pragma unroll
        for (int ks = 0; ks < 4; ++ks) {
            #pragma unroll
            for (int mt4 = 0; mt4 < 4; ++mt4) {
                f16x8 bf = *(const f16x8*)(cur + (size_t)((mt4 * 4 + ks) * 64 + lane) * 8);
                acc[mt4] = __builtin_amdgcn_mfma_f32_16x16x32_f16(af[ks], bf, acc[mt4], 0, 0, 0);
            }
        }
        #pragma unroll
        for (int mt4 = 0; mt4 < 4; ++mt4) {
            float sm_ = sqm[m0 + mt4 * 16 + l15];   // = |xm|^2 + DBIAS
            #pragma unroll
            for (int reg = 0; reg < 4; ++reg) {     // D row = q (A free dim)
                int q = wv * 16 + quad * 4 + reg;
                Dt[q * 68 + mt4 * 16 + l15] = sm_ - 2.f * acc[mt4][reg];
            }
        }
        __syncthreads();                            // Dt(s) visible
        // per-lane top-24 over subset m%4==r: branch-free u32 min/max chain.
        // key = (quantized positive distance, 23 bits) | (m>>2, 9 bits);
        // granularity 2^-6 at |key| in [256,512) -- far below rank gaps.
        #pragma unroll
        for (int i2 = 0; i2 < 16; ++i2) {
            int mi = (i2 << 2) + r;
            unsigned bits = __float_as_uint(Dt[qi * 68 + mi]);
            unsigned key = (bits & 0xFFFFFE00u) | (unsigned)(s * 16 + i2);
            #pragma unroll
            for (int sl = 0; sl < KEEP; ++sl) {
                unsigned lo = bd[sl] <= key ? bd[sl] : key;
                unsigned hi = bd[sl] <= key ? key : bd[sl];
                bd[sl] = lo; key = hi;
            }
        }
    }

    // ---- fp64 refinement from fp32 xT rows (exact vs numpy) ----
    int bm[KEEP];
    #pragma unroll
    for (int i = 0; i < KEEP; ++i) bm[i] = (int)((bd[i] & 0x1FFu) << 2) | r;
    double dd[KEEP];
    #pragma unroll
    for (int i = 0; i < KEEP; ++i) dd[i] = 0.0;
    const float* xTb = xT + (size_t)b * NPT * CIN;
    const float* qrow = xTb + (size_t)(q0 + qi) * CIN;
    #pragma unroll 1
    for (int ch = 0; ch < 8; ++ch) {
        double qd[16];
        #pragma unroll
        for (int j = 0; j < 4; ++j) {
            float4 qv = *(const float4*)&qrow[ch * 16 + 4 * j];
            qd[4 * j] = (double)qv.x; qd[4 * j + 1] = (double)qv.y;
            qd[4 * j + 2] = (double)qv.z; qd[4 * j + 3] = (double)qv.w;
        }
        #pragma unroll
        for (int i = 0; i < KEEP; ++i) {
            const float* mrow = xTb + (size_t)bm[i] * CIN + ch * 16;
            float4 ma = *(const float4*)&mrow[0];
            float4 mb = *(const float4*)&mrow[4];
            float4 mc = *(const float4*)&mrow[8];
            float4 md = *(const float4*)&mrow[12];
            double ss = dd[i], d0;
            d0 = qd[0]  - (double)ma.x; ss = fma(d0, d0, ss);
            d0 = qd[1]  - (double)ma.y; ss = fma(d0, d0, ss);
            d0 = qd[2]  - (double)ma.z; ss = fma(d0, d0, ss);
            d0 = qd[3]  - (double)ma.w; ss = fma(d0, d0, ss);
            d0 = qd[4]  - (double)mb.x; ss = fma(d0, d0, ss);
            d0 = qd[5]  - (double)mb.y; ss = fma(d0, d0, ss);
            d0 = qd[6]  - (double)mb.z; ss = fma(d0, d0, ss);
            d0 = qd[7]  - (double)mb.w; ss = fma(d0, d0, ss);
            d0 = qd[8]  - (double)mc.x; ss = fma(d0, d0, ss);
            d0 = qd[9]  - (double)mc.y; ss = fma(d0, d0, ss);
            d0 = qd[10] - (double)mc.z; ss = fma(d0, d0, ss);
            d0 = qd[11] - (double)mc.w; ss = fma(d0, d0, ss);
            d0 = qd[12] - (double)md.x; ss = fma(d0, d0, ss);
            d0 = qd[13] - (double)md.y; ss = fma(d0, d0, ss);
            d0 = qd[14] - (double)md.z; ss = fma(d0, d0, ss);
            d0 = qd[15] - (double)md.w; ss = fma(d0, d0, ss);
            dd[i] = ss;
        }
    }

    // ---- exact selection over 96 candidates: 2 phases of 32 queries ----
    // layout [slot][33] lane-major: conflict-free scans.
    double* rD = (double*)smraw;                   // 96*33*8 = 25344 B
    int*    rI = (int*)(smraw + 25344);            // 96*33*4 = 12672 B
    #pragma unroll 1
    for (int ph = 0; ph < 2; ++ph) {
        __syncthreads();
        if ((qi >> 5) == ph) {
            const int lq = qi & 31;
            #pragma unroll
            for (int i = 0; i < KEEP; ++i) {
                int slot = r * KEEP + i;
                rD[slot * 33 + lq] = dd[i];
                rI[slot * 33 + lq] = bm[i];
            }
        }
        __syncthreads();
        if (t < 32) {
            const int n = q0 + ph * 32 + t;
            int* dst = knn_out + ((size_t)b * NPT + n) * KNN;
            #pragma unroll 1
            for (int o = 0; o < KNN; ++o) {
                double best = rD[t]; int bp = 0;
                #pragma unroll 1
                for (int j2 = 1; j2 < CAND; ++j2) {
                    double v = rD[j2 * 33 + t];
                    if (v < best) { best = v; bp = j2; }
                }
                dst[o] = rI[bp * 33 + t];
                rD[bp * 33 + t] = 1e300;
            }
        }
    }
}

// ------------------------------------------------- u/v GEMM: uT/vT[b][n][o]
__global__ __launch_bounds__(256) void uv_gemm(const float* __restrict__ x,
                                               const float* __restrict__ W,
                                               float* __restrict__ uT,
                                               float* __restrict__ vT) {
    __shared__ float Ax[32 * 64];
    __shared__ float Bu[32 * 68];
    __shared__ float Bv[32 * 68];

    const int b  = blockIdx.z;
    const int n0 = blockIdx.x * 64;
    const int o0 = blockIdx.y * 64;
    const int t  = threadIdx.x;
    const int tx = t & 15, ty = t >> 4;
    const float* xb = x + (size_t)b * CIN * NPT;

    float au[4][4], av_[4][4];
    #pragma unroll
    for (int i = 0; i < 4; ++i)
        #pragma unroll
        for (int j = 0; j < 4; ++j) { au[i][j] = 0.f; av_[i][j] = 0.f; }

    #pragma unroll 1
    for (int kc = 0; kc < 4; ++kc) {
        const int c0 = kc * 32;
        __syncthreads();
        #pragma unroll
        for (int e = 0; e < 2; ++e) {
            int f = e * 256 + t;
            int cz = f >> 4, ni = (f & 15) << 2;
            *(float4*)&Ax[(cz << 6) + ni] = *(const float4*)&xb[(size_t)(c0 + cz) * NPT + n0 + ni];
        }
        #pragma unroll
        for (int e = 0; e < 8; ++e) {
            int ii = e * 256 + t;
            int cz = ii & 31, oj = ii >> 5;
            float w1 = W[(size_t)(o0 + oj) * 256 + c0 + cz];
            float w2 = W[(size_t)(o0 + oj) * 256 + 128 + c0 + cz];
            Bu[cz * 68 + oj] = w1 - w2;
            Bv[cz * 68 + oj] = w2;
        }
        __syncthreads();
        #pragma unroll 8
        for (int cz = 0; cz < 32; ++cz) {
            const float4 a4 = *(const float4*)&Ax[(cz << 6) + (tx << 2)];
            float bu0 = Bu[cz * 68 + (ty << 2) + 0], bv0 = Bv[cz * 68 + (ty << 2) + 0];
            float bu1 = Bu[cz * 68 + (ty << 2) + 1], bv1 = Bv[cz * 68 + (ty << 2) + 1];
            float bu2 = Bu[cz * 68 + (ty << 2) + 2], bv2 = Bv[cz * 68 + (ty << 2) + 2];
            float bu3 = Bu[cz * 68 + (ty << 2) + 3], bv3 = Bv[cz * 68 + (ty << 2) + 3];
            au[0][0] += a4.x * bu0; au[0][1] += a4.x * bu1; au[0][2] += a4.x * bu2; au[0][3] += a4.x * bu3;
            au[1][0] += a4.y * bu0; au[1][1] += a4.y * bu1; au[1][2] += a4.y * bu2; au[1][3] += a4.y * bu3;
            au[2][0] += a4.z * bu0; au[2][1] += a4.z * bu1; au[2][2] += a4.z * bu2; au[2][3] += a4.z * bu3;
            au[3][0] += a4.w * bu0; au[3][1] += a4.w * bu1; au[3][2] += a4.w * bu2; au[3][3] += a4.w * bu3;
            av_[0][0] += a4.x * bv0; av_[0][1] += a4.x * bv1; av_[0][2] += a4.x * bv2; av_[0][3] += a4.x * bv3;
            av_[1][0] += a4.y * bv0; av_[1][1] += a4.y * bv1; av_[1][2] += a4.y * bv2; av_[1][3] += a4.y * bv3;
            av_[2][0] += a4.z * bv0; av_[2][1] += a4.z * bv1; av_[2][2] += a4.z * bv2; av_[2][3] += a4.z * bv3;
            av_[3][0] += a4.w * bv0; av_[3][1] += a4.w * bv1; av_[3][2] += a4.w * bv2; av_[3][3] += a4.w * bv3;
        }
    }
    #pragma unroll
    for (int i = 0; i < 4; ++i) {
        int n = n0 + (tx << 2) + i;
        size_t base = ((size_t)b * NPT + n) * COUT + o0 + (ty << 2);
        float4 u4 = {au[i][0], au[i][1], au[i][2], au[i][3]};
        float4 v4 = {av_[i][0], av_[i][1], av_[i][2], av_[i][3]};
        *(float4*)&uT[base] = u4;
        *(float4*)&vT[base] = v4;
    }
}

// ------------------------------------------------- BN statistics (pass A)
__global__ __launch_bounds__(256) void stats_kernel(const float* __restrict__ uT,
                                                    const float* __restrict__ vT,
                                                    const int* __restrict__ knn_in,
                                                    double* __restrict__ gsum) {
    __shared__ int sidx[64 * KNN];
    const int b  = blockIdx.y;
    const int n0 = blockIdx.x * 64;
    const int o  = threadIdx.x;
    for (int e = o; e < 64 * KNN; e += 256)
        sidx[e] = knn_in[((size_t)b * NPT + n0) * KNN + e];
    __syncthreads();
    const float* ub = uT + ((size_t)b * NPT + n0) * COUT + o;
    const float* vb = vT + (size_t)b * NPT * COUT + o;
    double s1 = 0.0, s2 = 0.0;
    #pragma unroll 1
    for (int s = 0; s < 64; ++s) {
        float u = ub[(size_t)s * COUT];
        #pragma unroll
        for (int j = 0; j < KNN; ++j) {
            float y = u + vb[(size_t)sidx[s * KNN + j] * COUT];
            s1 += (double)y;
            s2 = fma((double)y, (double)y, s2);
        }
    }
    atomicAdd(&gsum[o], s1);
    atomicAdd(&gsum[COUT + o], s2);
}

// ------------------------------------------------- fold stats -> scale/shift
__global__ void finalize_kernel(const double* __restrict__ gsum,
                                const float* __restrict__ gamma,
                                const float* __restrict__ beta,
                                float* __restrict__ st) {
    const int o = threadIdx.x;
    const double M = (double)B_ * NPT * KNN;
    double mean = gsum[o] / M;
    double var  = gsum[COUT + o] / M - mean * mean;
    float inv = 1.0f / sqrtf((float)var + EPS);
    float s = gamma[o] * inv;
    st[o] = s;
    st[COUT + o] = beta[o] - (float)mean * s;
}

// ------------------------------------------------- gather+affine+relu+max
__global__ __launch_bounds__(256, 2) void out_kernel(const float* __restrict__ uT,
                                                     const float* __restrict__ vT,
                                                     const int* __restrict__ knn_in,
                                                     const float* __restrict__ st,
                                                     float* __restrict__ out) {
    __shared__ int sidx[64 * KNN];
    __shared__ float zt[256 * 68];
    const int b  = blockIdx.y;
    const int n0 = blockIdx.x * 64;
    const int o  = threadIdx.x;
    for (int e = o; e < 64 * KNN; e += 256)
        sidx[e] = knn_in[((size_t)b * NPT + n0) * KNN + e];
    __syncthreads();
    const float s  = st[o];
    const float tt = st[COUT + o];
    const float* ub = uT + ((size_t)b * NPT + n0) * COUT + o;
    const float* vb = vT + (size_t)b * NPT * COUT + o;
    #pragma unroll 1
    for (int si = 0; si < 64; ++si) {
        float u = ub[(size_t)si * COUT];
        float ymax = -3e38f, ymin = 3e38f;
        #pragma unroll
        for (int j = 0; j < KNN; ++j) {
            float y = u + vb[(size_t)sidx[si * KNN + j] * COUT];
            ymax = fmaxf(ymax, y);
            ymin = fminf(ymin, y);
        }
        float z1 = fmaxf(s * ymax + tt, 0.f);
        float z2 = fmaxf(s * ymin + tt, 0.f);
        zt[o * 68 + si] = fmaxf(z1, z2);
    }
    __syncthreads();
    float* dst = out + ((size_t)b * COUT + o) * NPT + n0;
    #pragma unroll
    for (int i = 0; i < 16; ++i)
        *(float4*)&dst[i * 4] = *(const float4*)&zt[o * 68 + i * 4];
}

extern "C" void kernel_launch(void* const* d_in, const int* in_sizes, int n_in,
                              void* d_out, int out_size, void* d_ws, size_t ws_size,
                              hipStream_t stream) {
    const float* x     = (const float*)d_in[0];
    const float* W     = (const float*)d_in[1];
    const float* gamma = (const float*)d_in[2];
    const float* beta  = (const float*)d_in[3];
    float* out = (float*)d_out;
    char* ws = (char*)d_ws;
    float*     sqh  = (float*)(ws + SQ_OFF);
    int*       idx  = (int*)(ws + IDX_OFF);
    float*     xT   = (float*)(ws + XT_OFF);    // aliases uT
    _Float16*  xhT  = (_Float16*)(ws + XHT_OFF);// aliases vT
    float*     uT   = (float*)(ws + UT_OFF);
    float*     vT   = (float*)(ws + VT_OFF);
    double*    gsum = (double*)(ws + GS_OFF);
    float*     st   = (float*)(ws + ST_OFF);

    hipMemsetAsync(gsum, 0, 2 * COUT * sizeof(double), stream);
    prep_kernel<<<dim3(32, 16), 256, 0, stream>>>(x, xT, xhT, sqh);
    knn_kernel<<<dim3(32, 16), 256, 0, stream>>>(xhT, xT, sqh, idx);
    // uv_gemm AFTER knn: uT/vT regions alias xT/xhT
    uv_gemm<<<dim3(32, 4, 16), 256, 0, stream>>>(x, W, uT, vT);
    stats_kernel<<<dim3(32, 16), 256, 0, stream>>>(uT, vT, idx, gsum);
    finalize_kernel<<<1, 256, 0, stream>>>(gsum, gamma, beta, st);
    out_kernel<<<dim3(32, 16), 256, 0, stream>>>(uT, vT, idx, st, out);
}

// Round 6
// 579.166 us; speedup vs baseline: 1.8621x; 1.2277x over previous
//
#include <hip/hip_runtime.h>

#define B_   16
#define CIN  128
#define NPT  2048
#define COUT 256
#define KNN  20
#define KEEP 24
#define CAND 96
#define EPS  1e-5f
#define DBIAS 256.0f   // must exceed max_q |x_q|^2 (chi2_128 max ~210 over 32k)

// workspace byte offsets
#define SQ_OFF   0ull                          // sqh: 32768 f (fp16-rounded |x|^2)
#define IDX_OFF  131072ull                     // 16*2048*20 i32
#define UT_OFF   2752512ull                    // 16*2048*256 f
#define VT_OFF   36306944ull                   // 16*2048*256 f
#define GS_OFF   69861376ull                   // 2*256 double
#define ST_OFF   69865472ull                   // 2*256 f
// xT[b][n][c] fp32 (16.8 MB) aliases uT; xhT[b][n][c] fp16 (8.4 MB) aliases vT.
// prep writes both; knn reads them; uv_gemm (runs after knn) overwrites.
#define XT_OFF   UT_OFF
#define XHT_OFF  VT_OFF

typedef _Float16 f16x8 __attribute__((ext_vector_type(8)));
typedef float    f32x4 __attribute__((ext_vector_type(4)));

// ---------------------------------------------------- prep: xT, xhT, sqh
__global__ __launch_bounds__(256) void prep_kernel(const float* __restrict__ x,
                                                   float* __restrict__ xT,
                                                   _Float16* __restrict__ xhT,
                                                   float* __restrict__ sqh) {
    __shared__ float Ls[128 * 68];
    __shared__ float ps[4 * 64];
    const int b = blockIdx.y, n0 = blockIdx.x * 64, t = threadIdx.x;
    const float* xb = x + (size_t)b * CIN * NPT;
    #pragma unroll
    for (int e = 0; e < 8; ++e) {              // 2048 float4 loads, coalesced
        int f = e * 256 + t;
        int c = f >> 4, n4 = (f & 15) << 2;
        *(float4*)&Ls[c * 68 + n4] = *(const float4*)&xb[(size_t)c * NPT + n0 + n4];
    }
    __syncthreads();
    {                                          // sq partials on fp16-rounded vals
        int nl = t & 63, part = t >> 6;
        float acc = 0.f;
        #pragma unroll
        for (int j = 0; j < 32; ++j) {
            float vh = (float)(_Float16)Ls[(part * 32 + j) * 68 + nl];
            acc += vh * vh;
        }
        ps[part * 64 + nl] = acc;
    }
    #pragma unroll
    for (int e = 0; e < 2; ++e) {              // transpose writes: (nl, 16-c chunk)
        int u = e * 256 + t;
        int nl = u >> 3, ck = (u & 7) << 4;
        float vv[16];
        #pragma unroll
        for (int j = 0; j < 16; ++j) vv[j] = Ls[(ck + j) * 68 + nl];
        size_t row = (size_t)b * NPT + n0 + nl;
        #pragma unroll
        for (int j = 0; j < 4; ++j) {
            float4 w = {vv[4 * j], vv[4 * j + 1], vv[4 * j + 2], vv[4 * j + 3]};
            *(float4*)&xT[row * CIN + ck + 4 * j] = w;
        }
        f16x8 h0, h1;
        #pragma unroll
        for (int j = 0; j < 8; ++j) { h0[j] = (_Float16)vv[j]; h1[j] = (_Float16)vv[8 + j]; }
        *(f16x8*)&xhT[row * CIN + ck] = h0;
        *(f16x8*)&xhT[row * CIN + ck + 8] = h1;
    }
    __syncthreads();
    if (t < 64) sqh[b * NPT + n0 + t] = ps[t] + ps[64 + t] + ps[128 + t] + ps[192 + t];
}

// -------------------------------------------- fragment staging via DMA
__device__ __forceinline__ void stage_pts(const _Float16* __restrict__ xhb,
                                          _Float16* buf, int base_n, int t) {
    const int l15 = t & 15, ks = t >> 6;
    const int quad = (t >> 4) & 3;
    const int c = ks * 32 + quad * 8;
    #pragma unroll
    for (int e = 0; e < 4; ++e) {
        const int n = base_n + e * 16 + l15;
        const _Float16* src = xhb + (size_t)n * CIN + c;
        _Float16* dst = buf + (size_t)(e * 256 + (t & 192)) * 8;   // wave-uniform base
        __builtin_amdgcn_global_load_lds(
            (const __attribute__((address_space(1))) void*)src,
            (__attribute__((address_space(3))) void*)dst, 16, 0, 0);
    }
}

// ---------------------------------------------------------------- KNN
// fp16 MFMA distance tiles + per-lane top-24 via packed-float min/max chain
// (23-bit quantized POSITIVE key | 9-bit subset index) + fp64 refinement of
// 96 candidates + parallel rank-count selection -> exact top-20 set.
__global__ __launch_bounds__(256, 2) void knn_kernel(const _Float16* __restrict__ xhT,
                                                     const float* __restrict__ xT,
                                                     const float* __restrict__ sqh,
                                                     int* __restrict__ knn_out) {
    __shared__ char smraw[58368];
    _Float16* bufA = (_Float16*)smraw;              // 16 KB: A frags, then B dbuf
    _Float16* bufB = (_Float16*)(smraw + 16384);    // 16 KB: B frags
    float*    Dt   = (float*)(smraw + 32768);       // 64 x 68 f
    float*    sqm  = (float*)(smraw + 50176);       // 2048 f (biased +DBIAS)

    const int b  = blockIdx.y;
    const int q0 = blockIdx.x * 64;
    const int t  = threadIdx.x;
    const int lane = t & 63, wv = t >> 6;
    const int l15 = lane & 15, quad = lane >> 4;
    const _Float16* xhb = xhT + (size_t)b * NPT * CIN;

    // Dt[q][m] = |xm|^2 + DBIAS - 2<q,m>  (drops |xq|^2: constant per query).
    // DBIAS > max |xq|^2 keeps Dt > 0 so float bit order == value order.
    #pragma unroll
    for (int e = 0; e < 8; ++e)
        sqm[e * 256 + t] = sqh[b * NPT + e * 256 + t] + DBIAS;

    stage_pts(xhb, bufA, q0, t);                    // A fragments (64 queries)
    __syncthreads();
    f16x8 af[4];
    #pragma unroll
    for (int ks = 0; ks < 4; ++ks)
        af[ks] = *(const f16x8*)(bufA + (size_t)((wv * 4 + ks) * 64 + lane) * 8);
    stage_pts(xhb, bufB, 0, t);                     // B stage 0

    float bd[KEEP];
    #pragma unroll
    for (int i = 0; i < KEEP; ++i) bd[i] = 3.0e38f;
    const int qi = t >> 2, r = t & 3;

    #pragma unroll 1
    for (int s = 0; s < 32; ++s) {
        __syncthreads();                            // buf[s&1] ready; Dt consumed
        _Float16* cur = (s & 1) ? bufA : bufB;
        if (s < 31) stage_pts(xhb, (s & 1) ? bufB : bufA, (s + 1) * 64, t);
        const int m0 = s * 64;
        f32x4 acc[4];
        #pragma unroll
        for (int mt4 = 0; mt4 < 4; ++mt4) acc[mt4] = (f32x4){0.f, 0.f, 0.f, 0.f};
        #pragma unroll
        for (int ks = 0; ks < 4; ++ks) {
            #pragma unroll
            for (int mt4 = 0; mt4 < 4; ++mt4) {
                f16x8 bf = *(const f16x8*)(cur + (size_t)((mt4 * 4 + ks) * 64 + lane) * 8);
                acc[mt4] = __builtin_amdgcn_mfma_f32_16x16x32_f16(af[ks], bf, acc[mt4], 0, 0, 0);
            }
        }
        #pragma unroll
        for (int mt4 = 0; mt4 < 4; ++mt4) {
            float sm_ = sqm[m0 + mt4 * 16 + l15];   // = |xm|^2 + DBIAS
            #pragma unroll
            for (int reg = 0; reg < 4; ++reg) {     // D row = q (A free dim)
                int q = wv * 16 + quad * 4 + reg;
                Dt[q * 68 + mt4 * 16 + l15] = sm_ - 2.f * acc[mt4][reg];
            }
        }
        __syncthreads();                            // Dt(s) visible
        // per-lane top-24 over subset m%4==r: branch-free float min/max chain.
        // key = (quantized positive distance, 23 bits) | (m>>2, 9 bits);
        // positive floats: fmin/fmax ordering == u32 ordering on the packed key.
        #pragma unroll
        for (int i2 = 0; i2 < 16; ++i2) {
            int mi = (i2 << 2) + r;
            unsigned bits = __float_as_uint(Dt[qi * 68 + mi]);
            float key = __uint_as_float((bits & 0xFFFFFE00u) | (unsigned)(s * 16 + i2));
            #pragma unroll
            for (int sl = 0; sl < KEEP; ++sl) {
                float lo = fminf(bd[sl], key);
                float hi = fmaxf(bd[sl], key);
                bd[sl] = lo; key = hi;
            }
        }
    }

    // ---- fp64 refinement from fp32 xT rows (exact vs numpy) ----
    int bm[KEEP];
    #pragma unroll
    for (int i = 0; i < KEEP; ++i)
        bm[i] = (int)((__float_as_uint(bd[i]) & 0x1FFu) << 2) | r;
    double dd[KEEP];
    #pragma unroll
    for (int i = 0; i < KEEP; ++i) dd[i] = 0.0;
    const float* xTb = xT + (size_t)b * NPT * CIN;
    const float* qrow = xTb + (size_t)(q0 + qi) * CIN;
    #pragma unroll 1
    for (int ch = 0; ch < 8; ++ch) {
        double qd[16];
        #pragma unroll
        for (int j = 0; j < 4; ++j) {
            float4 qv = *(const float4*)&qrow[ch * 16 + 4 * j];
            qd[4 * j] = (double)qv.x; qd[4 * j + 1] = (double)qv.y;
            qd[4 * j + 2] = (double)qv.z; qd[4 * j + 3] = (double)qv.w;
        }
        #pragma unroll
        for (int i = 0; i < KEEP; ++i) {
            const float* mrow = xTb + (size_t)bm[i] * CIN + ch * 16;
            float4 ma = *(const float4*)&mrow[0];
            float4 mb = *(const float4*)&mrow[4];
            float4 mc = *(const float4*)&mrow[8];
            float4 md = *(const float4*)&mrow[12];
            double ss = dd[i], d0;
            d0 = qd[0]  - (double)ma.x; ss = fma(d0, d0, ss);
            d0 = qd[1]  - (double)ma.y; ss = fma(d0, d0, ss);
            d0 = qd[2]  - (double)ma.z; ss = fma(d0, d0, ss);
            d0 = qd[3]  - (double)ma.w; ss = fma(d0, d0, ss);
            d0 = qd[4]  - (double)mb.x; ss = fma(d0, d0, ss);
            d0 = qd[5]  - (double)mb.y; ss = fma(d0, d0, ss);
            d0 = qd[6]  - (double)mb.z; ss = fma(d0, d0, ss);
            d0 = qd[7]  - (double)mb.w; ss = fma(d0, d0, ss);
            d0 = qd[8]  - (double)mc.x; ss = fma(d0, d0, ss);
            d0 = qd[9]  - (double)mc.y; ss = fma(d0, d0, ss);
            d0 = qd[10] - (double)mc.z; ss = fma(d0, d0, ss);
            d0 = qd[11] - (double)mc.w; ss = fma(d0, d0, ss);
            d0 = qd[12] - (double)md.x; ss = fma(d0, d0, ss);
            d0 = qd[13] - (double)md.y; ss = fma(d0, d0, ss);
            d0 = qd[14] - (double)md.z; ss = fma(d0, d0, ss);
            d0 = qd[15] - (double)md.w; ss = fma(d0, d0, ss);
            dd[i] = ss;
        }
    }

    // ---- exact parallel selection: rank-count over 96 candidates ----
    // All dd distinct (continuous data, distinct m per query) => top-20 set is
    // {i : rank_i < 20}, rank_i = #{j : dd_j < dd_i}; dst[rank] ascending.
    double* rD = (double*)smraw;                   // 96*33*8 = 25344 B
    #pragma unroll 1
    for (int ph = 0; ph < 2; ++ph) {
        __syncthreads();                           // rD region free / prev phase done
        const int lq = qi & 31;
        if ((qi >> 5) == ph) {
            #pragma unroll
            for (int i = 0; i < KEEP; ++i)
                rD[(r * KEEP + i) * 33 + lq] = dd[i];
        }
        __syncthreads();                           // rD visible
        if ((qi >> 5) == ph) {
            int cnt[KEEP];
            #pragma unroll
            for (int i = 0; i < KEEP; ++i) cnt[i] = 0;
            #pragma unroll 4
            for (int j = 0; j < CAND; ++j) {
                double dj = rD[j * 33 + lq];
                #pragma unroll
                for (int i = 0; i < KEEP; ++i)
                    cnt[i] += (dj < dd[i]) ? 1 : 0;
            }
            int* dst = knn_out + ((size_t)b * NPT + q0 + qi) * KNN;
            #pragma unroll
            for (int i = 0; i < KEEP; ++i)
                if (cnt[i] < KNN) dst[cnt[i]] = bm[i];
        }
    }
}

// ------------------------------------------------- u/v GEMM: uT/vT[b][n][o]
__global__ __launch_bounds__(256) void uv_gemm(const float* __restrict__ x,
                                               const float* __restrict__ W,
                                               float* __restrict__ uT,
                                               float* __restrict__ vT) {
    __shared__ float Ax[32 * 64];
    __shared__ float Bu[32 * 68];
    __shared__ float Bv[32 * 68];

    const int b  = blockIdx.z;
    const int n0 = blockIdx.x * 64;
    const int o0 = blockIdx.y * 64;
    const int t  = threadIdx.x;
    const int tx = t & 15, ty = t >> 4;
    const float* xb = x + (size_t)b * CIN * NPT;

    float au[4][4], av_[4][4];
    #pragma unroll
    for (int i = 0; i < 4; ++i)
        #pragma unroll
        for (int j = 0; j < 4; ++j) { au[i][j] = 0.f; av_[i][j] = 0.f; }

    #pragma unroll 1
    for (int kc = 0; kc < 4; ++kc) {
        const int c0 = kc * 32;
        __syncthreads();
        #pragma unroll
        for (int e = 0; e < 2; ++e) {
            int f = e * 256 + t;
            int cz = f >> 4, ni = (f & 15) << 2;
            *(float4*)&Ax[(cz << 6) + ni] = *(const float4*)&xb[(size_t)(c0 + cz) * NPT + n0 + ni];
        }
        #pragma unroll
        for (int e = 0; e < 8; ++e) {
            int ii = e * 256 + t;
            int cz = ii & 31, oj = ii >> 5;
            float w1 = W[(size_t)(o0 + oj) * 256 + c0 + cz];
            float w2 = W[(size_t)(o0 + oj) * 256 + 128 + c0 + cz];
            Bu[cz * 68 + oj] = w1 - w2;
            Bv[cz * 68 + oj] = w2;
        }
        __syncthreads();
        #pragma unroll 8
        for (int cz = 0; cz < 32; ++cz) {
            const float4 a4 = *(const float4*)&Ax[(cz << 6) + (tx << 2)];
            float bu0 = Bu[cz * 68 + (ty << 2) + 0], bv0 = Bv[cz * 68 + (ty << 2) + 0];
            float bu1 = Bu[cz * 68 + (ty << 2) + 1], bv1 = Bv[cz * 68 + (ty << 2) + 1];
            float bu2 = Bu[cz * 68 + (ty << 2) + 2], bv2 = Bv[cz * 68 + (ty << 2) + 2];
            float bu3 = Bu[cz * 68 + (ty << 2) + 3], bv3 = Bv[cz * 68 + (ty << 2) + 3];
            au[0][0] += a4.x * bu0; au[0][1] += a4.x * bu1; au[0][2] += a4.x * bu2; au[0][3] += a4.x * bu3;
            au[1][0] += a4.y * bu0; au[1][1] += a4.y * bu1; au[1][2] += a4.y * bu2; au[1][3] += a4.y * bu3;
            au[2][0] += a4.z * bu0; au[2][1] += a4.z * bu1; au[2][2] += a4.z * bu2; au[2][3] += a4.z * bu3;
            au[3][0] += a4.w * bu0; au[3][1] += a4.w * bu1; au[3][2] += a4.w * bu2; au[3][3] += a4.w * bu3;
            av_[0][0] += a4.x * bv0; av_[0][1] += a4.x * bv1; av_[0][2] += a4.x * bv2; av_[0][3] += a4.x * bv3;
            av_[1][0] += a4.y * bv0; av_[1][1] += a4.y * bv1; av_[1][2] += a4.y * bv2; av_[1][3] += a4.y * bv3;
            av_[2][0] += a4.z * bv0; av_[2][1] += a4.z * bv1; av_[2][2] += a4.z * bv2; av_[2][3] += a4.z * bv3;
            av_[3][0] += a4.w * bv0; av_[3][1] += a4.w * bv1; av_[3][2] += a4.w * bv2; av_[3][3] += a4.w * bv3;
        }
    }
    #pragma unroll
    for (int i = 0; i < 4; ++i) {
        int n = n0 + (tx << 2) + i;
        size_t base = ((size_t)b * NPT + n) * COUT + o0 + (ty << 2);
        float4 u4 = {au[i][0], au[i][1], au[i][2], au[i][3]};
        float4 v4 = {av_[i][0], av_[i][1], av_[i][2], av_[i][3]};
        *(float4*)&uT[base] = u4;
        *(float4*)&vT[base] = v4;
    }
}

// ------------------------------------------------- BN statistics (pass A)
__global__ __launch_bounds__(256) void stats_kernel(const float* __restrict__ uT,
                                                    const float* __restrict__ vT,
                                                    const int* __restrict__ knn_in,
                                                    double* __restrict__ gsum) {
    __shared__ int sidx[64 * KNN];
    const int b  = blockIdx.y;
    const int n0 = blockIdx.x * 64;
    const int o  = threadIdx.x;
    for (int e = o; e < 64 * KNN; e += 256)
        sidx[e] = knn_in[((size_t)b * NPT + n0) * KNN + e];
    __syncthreads();
    const float* ub = uT + ((size_t)b * NPT + n0) * COUT + o;
    const float* vb = vT + (size_t)b * NPT * COUT + o;
    double s1 = 0.0, s2 = 0.0;
    #pragma unroll 1
    for (int s = 0; s < 64; ++s) {
        float u = ub[(size_t)s * COUT];
        #pragma unroll
        for (int j = 0; j < KNN; ++j) {
            float y = u + vb[(size_t)sidx[s * KNN + j] * COUT];
            s1 += (double)y;
            s2 = fma((double)y, (double)y, s2);
        }
    }
    atomicAdd(&gsum[o], s1);
    atomicAdd(&gsum[COUT + o], s2);
}

// ------------------------------------------------- fold stats -> scale/shift
__global__ void finalize_kernel(const double* __restrict__ gsum,
                                const float* __restrict__ gamma,
                                const float* __restrict__ beta,
                                float* __restrict__ st) {
    const int o = threadIdx.x;
    const double M = (double)B_ * NPT * KNN;
    double mean = gsum[o] / M;
    double var  = gsum[COUT + o] / M - mean * mean;
    float inv = 1.0f / sqrtf((float)var + EPS);
    float s = gamma[o] * inv;
    st[o] = s;
    st[COUT + o] = beta[o] - (float)mean * s;
}

// ------------------------------------------------- gather+affine+relu+max
__global__ __launch_bounds__(256, 2) void out_kernel(const float* __restrict__ uT,
                                                     const float* __restrict__ vT,
                                                     const int* __restrict__ knn_in,
                                                     const float* __restrict__ st,
                                                     float* __restrict__ out) {
    __shared__ int sidx[64 * KNN];
    __shared__ float zt[256 * 68];
    const int b  = blockIdx.y;
    const int n0 = blockIdx.x * 64;
    const int o  = threadIdx.x;
    for (int e = o; e < 64 * KNN; e += 256)
        sidx[e] = knn_in[((size_t)b * NPT + n0) * KNN + e];
    __syncthreads();
    const float s  = st[o];
    const float tt = st[COUT + o];
    const float* ub = uT + ((size_t)b * NPT + n0) * COUT + o;
    const float* vb = vT + (size_t)b * NPT * COUT + o;
    #pragma unroll 1
    for (int si = 0; si < 64; ++si) {
        float u = ub[(size_t)si * COUT];
        float ymax = -3e38f, ymin = 3e38f;
        #pragma unroll
        for (int j = 0; j < KNN; ++j) {
            float y = u + vb[(size_t)sidx[si * KNN + j] * COUT];
            ymax = fmaxf(ymax, y);
            ymin = fminf(ymin, y);
        }
        float z1 = fmaxf(s * ymax + tt, 0.f);
        float z2 = fmaxf(s * ymin + tt, 0.f);
        zt[o * 68 + si] = fmaxf(z1, z2);
    }
    __syncthreads();
    float* dst = out + ((size_t)b * COUT + o) * NPT + n0;
    #pragma unroll
    for (int i = 0; i < 16; ++i)
        *(float4*)&dst[i * 4] = *(const float4*)&zt[o * 68 + i * 4];
}

extern "C" void kernel_launch(void* const* d_in, const int* in_sizes, int n_in,
                              void* d_out, int out_size, void* d_ws, size_t ws_size,
                              hipStream_t stream) {
    const float* x     = (const float*)d_in[0];
    const float* W     = (const float*)d_in[1];
    const float* gamma = (const float*)d_in[2];
    const float* beta  = (const float*)d_in[3];
    float* out = (float*)d_out;
    char* ws = (char*)d_ws;
    float*     sqh  = (float*)(ws + SQ_OFF);
    int*       idx  = (int*)(ws + IDX_OFF);
    float*     xT   = (float*)(ws + XT_OFF);    // aliases uT
    _Float16*  xhT  = (_Float16*)(ws + XHT_OFF);// aliases vT
    float*     uT   = (float*)(ws + UT_OFF);
    float*     vT   = (float*)(ws + VT_OFF);
    double*    gsum = (double*)(ws + GS_OFF);
    float*     st   = (float*)(ws + ST_OFF);

    hipMemsetAsync(gsum, 0, 2 * COUT * sizeof(double), stream);
    prep_kernel<<<dim3(32, 16), 256, 0, stream>>>(x, xT, xhT, sqh);
    knn_kernel<<<dim3(32, 16), 256, 0, stream>>>(xhT, xT, sqh, idx);
    // uv_gemm AFTER knn: uT/vT regions alias xT/xhT
    uv_gemm<<<dim3(32, 4, 16), 256, 0, stream>>>(x, W, uT, vT);
    stats_kernel<<<dim3(32, 16), 256, 0, stream>>>(uT, vT, idx, gsum);
    finalize_kernel<<<1, 256, 0, stream>>>(gsum, gamma, beta, st);
    out_kernel<<<dim3(32, 16), 256, 0, stream>>>(uT, vT, idx, st, out);
}

// Round 8
// 409.290 us; speedup vs baseline: 2.6350x; 1.4151x over previous
//
#include <hip/hip_runtime.h>

#define B_   16
#define CIN  128
#define NPT  2048
#define COUT 256
#define KNN  20
#define KEEP 24
#define CAND 96
#define SIFT 32
#define EPS  1e-5f
#define DBIAS 256.0f   // must exceed max_q |x_q|^2 (chi2_128 max ~210 over 32k)

// workspace byte offsets
#define SQ_OFF   0ull                          // sqh: 32768 f (fp16-rounded |x|^2)
#define IDX_OFF  131072ull                     // 16*2048*20 i32
#define UT_OFF   2752512ull                    // 16*2048*256 f
#define VT_OFF   36306944ull                   // 16*2048*256 f
#define GS_OFF   69861376ull                   // 2*256 double
#define ST_OFF   69865472ull                   // 2*256 f
// optional fused-path buffers (only used when ws_size is large enough)
#define AMAX_OFF 69871616ull                   // 16*2048*256 f = 33554432
#define AMIN_OFF 103426048ull                  // 16*2048*256 f
#define WS_NEED_FUSED 136980480ull
// xT[b][n][c] fp32 (16.8 MB) aliases uT; xhT[b][n][c] fp16 (8.4 MB) aliases vT.
// prep writes both; knn reads them; uv_gemm (runs after knn) overwrites.
#define XT_OFF   UT_OFF
#define XHT_OFF  VT_OFF

typedef _Float16 f16x8 __attribute__((ext_vector_type(8)));
typedef float    f32x4 __attribute__((ext_vector_type(4)));

// ---------------------------------------------------- prep: xT, xhT, sqh
__global__ __launch_bounds__(256) void prep_kernel(const float* __restrict__ x,
                                                   float* __restrict__ xT,
                                                   _Float16* __restrict__ xhT,
                                                   float* __restrict__ sqh) {
    __shared__ float Ls[128 * 68];
    __shared__ float ps[4 * 64];
    const int b = blockIdx.y, n0 = blockIdx.x * 64, t = threadIdx.x;
    const float* xb = x + (size_t)b * CIN * NPT;
    #pragma unroll
    for (int e = 0; e < 8; ++e) {              // 2048 float4 loads, coalesced
        int f = e * 256 + t;
        int c = f >> 4, n4 = (f & 15) << 2;
        *(float4*)&Ls[c * 68 + n4] = *(const float4*)&xb[(size_t)c * NPT + n0 + n4];
    }
    __syncthreads();
    {                                          // sq partials on fp16-rounded vals
        int nl = t & 63, part = t >> 6;
        float acc = 0.f;
        #pragma unroll
        for (int j = 0; j < 32; ++j) {
            float vh = (float)(_Float16)Ls[(part * 32 + j) * 68 + nl];
            acc += vh * vh;
        }
        ps[part * 64 + nl] = acc;
    }
    #pragma unroll
    for (int e = 0; e < 2; ++e) {              // transpose writes: (nl, 16-c chunk)
        int u = e * 256 + t;
        int nl = u >> 3, ck = (u & 7) << 4;
        float vv[16];
        #pragma unroll
        for (int j = 0; j < 16; ++j) vv[j] = Ls[(ck + j) * 68 + nl];
        size_t row = (size_t)b * NPT + n0 + nl;
        #pragma unroll
        for (int j = 0; j < 4; ++j) {
            float4 w = {vv[4 * j], vv[4 * j + 1], vv[4 * j + 2], vv[4 * j + 3]};
            *(float4*)&xT[row * CIN + ck + 4 * j] = w;
        }
        f16x8 h0, h1;
        #pragma unroll
        for (int j = 0; j < 8; ++j) { h0[j] = (_Float16)vv[j]; h1[j] = (_Float16)vv[8 + j]; }
        *(f16x8*)&xhT[row * CIN + ck] = h0;
        *(f16x8*)&xhT[row * CIN + ck + 8] = h1;
    }
    __syncthreads();
    if (t < 64) sqh[b * NPT + n0 + t] = ps[t] + ps[64 + t] + ps[128 + t] + ps[192 + t];
}

// -------------------------------------------- fragment staging via DMA
__device__ __forceinline__ void stage_pts(const _Float16* __restrict__ xhb,
                                          _Float16* buf, int base_n, int t) {
    const int l15 = t & 15, ks = t >> 6;
    const int quad = (t >> 4) & 3;
    const int c = ks * 32 + quad * 8;
    #pragma unroll
    for (int e = 0; e < 4; ++e) {
        const int n = base_n + e * 16 + l15;
        const _Float16* src = xhb + (size_t)n * CIN + c;
        _Float16* dst = buf + (size_t)(e * 256 + (t & 192)) * 8;   // wave-uniform base
        __builtin_amdgcn_global_load_lds(
            (const __attribute__((address_space(1))) void*)src,
            (__attribute__((address_space(3))) void*)dst, 16, 0, 0);
    }
}

// ---------------------------------------------------------------- KNN
// fp16 MFMA distance tiles + per-lane top-24 (med3 pair-insert chain on
// packed positive keys: 21-bit chopped distance | 11-bit FULL m -> keys
// globally unique per query) + quantized pre-sift to 32/query + fp64
// refinement (8 rows/lane) + parallel rank-count -> exact top-20 set.
__global__ __launch_bounds__(256, 2) void knn_kernel(const _Float16* __restrict__ xhT,
                                                     const float* __restrict__ xT,
                                                     const float* __restrict__ sqh,
                                                     int* __restrict__ knn_out) {
    __shared__ char smraw[58368];
    _Float16* bufA = (_Float16*)smraw;              // 16 KB: A frags, then B dbuf
    _Float16* bufB = (_Float16*)(smraw + 16384);    // 16 KB: B frags
    float*    Dt   = (float*)(smraw + 32768);       // 64 x 68 f
    float*    sqm  = (float*)(smraw + 50176);       // 2048 f (biased +DBIAS)

    const int b  = blockIdx.y;
    const int q0 = blockIdx.x * 64;
    const int t  = threadIdx.x;
    const int lane = t & 63, wv = t >> 6;
    const int l15 = lane & 15, quad = lane >> 4;
    const _Float16* xhb = xhT + (size_t)b * NPT * CIN;

    // Dt[q][m] = |xm|^2 + DBIAS - 2<q,m>  (drops |xq|^2: constant per query).
    // DBIAS > max |xq|^2 keeps Dt > 0 so float bit order == value order.
    #pragma unroll
    for (int e = 0; e < 8; ++e)
        sqm[e * 256 + t] = sqh[b * NPT + e * 256 + t] + DBIAS;

    stage_pts(xhb, bufA, q0, t);                    // A fragments (64 queries)
    __syncthreads();
    f16x8 af[4];
    #pragma unroll
    for (int ks = 0; ks < 4; ++ks)
        af[ks] = *(const f16x8*)(bufA + (size_t)((wv * 4 + ks) * 64 + lane) * 8);
    stage_pts(xhb, bufB, 0, t);                     // B stage 0

    float bd[KEEP];
    #pragma unroll
    for (int i = 0; i < KEEP; ++i) bd[i] = 3.0e38f;
    const int qi = t >> 2, r = t & 3;

    #pragma unroll 1
    for (int s = 0; s < 32; ++s) {
        __syncthreads();                            // buf[s&1] ready; Dt consumed
        _Float16* cur = (s & 1) ? bufA : bufB;
        if (s < 31) stage_pts(xhb, (s & 1) ? bufB : bufA, (s + 1) * 64, t);
        const int m0 = s * 64;
        f32x4 acc[4];
        #pragma unroll
        for (int mt4 = 0; mt4 < 4; ++mt4) acc[mt4] = (f32x4){0.f, 0.f, 0.f, 0.f};
        #pragma unroll
        for (int ks = 0; ks < 4; ++ks) {
            #pragma unroll
            for (int mt4 = 0; mt4 < 4; ++mt4) {
                f16x8 bf = *(const f16x8*)(cur + (size_t)((mt4 * 4 + ks) * 64 + lane) * 8);
                acc[mt4] = __builtin_amdgcn_mfma_f32_16x16x32_f16(af[ks], bf, acc[mt4], 0, 0, 0);
            }
        }
        #pragma unroll
        for (int mt4 = 0; mt4 < 4; ++mt4) {
            float sm_ = sqm[m0 + mt4 * 16 + l15];   // = |xm|^2 + DBIAS
            #pragma unroll
            for (int reg = 0; reg < 4; ++reg) {     // D row = q (A free dim)
                int q = wv * 16 + quad * 4 + reg;
                Dt[q * 68 + mt4 * 16 + l15] = sm_ - 2.f * acc[mt4][reg];
            }
        }
        __syncthreads();                            // Dt(s) visible
        // per-lane top-24 over subset m%4==r: pair-insert via min/med3/max.
        // key = (chopped positive distance, 21 bits) | (full m, 11 bits):
        // m unique per query -> keys globally unique -> rank-count is a
        // permutation (no Surv collisions). positive floats: float order ==
        // u32 order on the packed key. chop granularity ~2^-4 at key~330 vs
        // ~0.9 local order-stat spacing: safe for keep-24 / sift-32 supersets.
        #pragma unroll
        for (int p = 0; p < 8; ++p) {
            int i2a = p * 2, i2b = p * 2 + 1;
            unsigned ba = __float_as_uint(Dt[qi * 68 + (i2a << 2) + r]);
            unsigned bb = __float_as_uint(Dt[qi * 68 + (i2b << 2) + r]);
            float k0 = __uint_as_float((ba & 0xFFFFF800u) | (unsigned)(m0 + (i2a << 2) + r));
            float k1 = __uint_as_float((bb & 0xFFFFF800u) | (unsigned)(m0 + (i2b << 2) + r));
            float lo = fminf(k0, k1), hi = fmaxf(k0, k1);
            #pragma unroll
            for (int sl = 0; sl < KEEP; ++sl) {
                float bv = bd[sl];
                bd[sl] = fminf(bv, lo);
                float med = __builtin_amdgcn_fmed3f(bv, lo, hi);  // lo<=hi
                hi = fmaxf(bv, hi);
                lo = med;
            }
        }
    }

    // ---- quantized pre-sift: rank-count the 96 packed keys per query ----
    float* Keys = (float*)smraw;                   // [64][97] f = 24832 B
    int*   Surv = (int*)(smraw + 24832);           // [64][33] i = 8448 B
    double* ddL = (double*)(smraw + 33280);        // [64][33] d = 16896 B
    #pragma unroll
    for (int i = 0; i < KEEP; ++i)
        Keys[qi * 97 + r * KEEP + i] = bd[i];
    __syncthreads();
    {
        int cnt[KEEP];
        #pragma unroll
        for (int i = 0; i < KEEP; ++i) cnt[i] = 0;
        #pragma unroll 4
        for (int j = 0; j < CAND; ++j) {
            float kj = Keys[qi * 97 + j];
            #pragma unroll
            for (int i = 0; i < KEEP; ++i)
                cnt[i] += (kj < bd[i]) ? 1 : 0;
        }
        __syncthreads();                           // Keys consumed; Surv region free
        #pragma unroll
        for (int i = 0; i < KEEP; ++i)
            if (cnt[i] < SIFT)
                Surv[qi * 33 + cnt[i]] = (int)(__float_as_uint(bd[i]) & 0x7FFu);
    }
    __syncthreads();

    // ---- fp64 refinement of 8 survivors per lane (exact vs numpy) ----
    int ms[8];
    #pragma unroll
    for (int k = 0; k < 8; ++k) ms[k] = Surv[qi * 33 + r * 8 + k] & 2047;
    double dd8[8];
    #pragma unroll
    for (int k = 0; k < 8; ++k) dd8[k] = 0.0;
    const float* xTb = xT + (size_t)b * NPT * CIN;
    const float* qrow = xTb + (size_t)(q0 + qi) * CIN;
    #pragma unroll 1
    for (int ch = 0; ch < 8; ++ch) {
        double qd[16];
        #pragma unroll
        for (int j = 0; j < 4; ++j) {
            float4 qv = *(const float4*)&qrow[ch * 16 + 4 * j];
            qd[4 * j] = (double)qv.x; qd[4 * j + 1] = (double)qv.y;
            qd[4 * j + 2] = (double)qv.z; qd[4 * j + 3] = (double)qv.w;
        }
        #pragma unroll
        for (int k = 0; k < 8; ++k) {
            const float* mrow = xTb + (size_t)ms[k] * CIN + ch * 16;
            float4 ma = *(const float4*)&mrow[0];
            float4 mb = *(const float4*)&mrow[4];
            float4 mc = *(const float4*)&mrow[8];
            float4 md = *(const float4*)&mrow[12];
            double ss = dd8[k], d0;
            d0 = qd[0]  - (double)ma.x; ss = fma(d0, d0, ss);
            d0 = qd[1]  - (double)ma.y; ss = fma(d0, d0, ss);
            d0 = qd[2]  - (double)ma.z; ss = fma(d0, d0, ss);
            d0 = qd[3]  - (double)ma.w; ss = fma(d0, d0, ss);
            d0 = qd[4]  - (double)mb.x; ss = fma(d0, d0, ss);
            d0 = qd[5]  - (double)mb.y; ss = fma(d0, d0, ss);
            d0 = qd[6]  - (double)mb.z; ss = fma(d0, d0, ss);
            d0 = qd[7]  - (double)mb.w; ss = fma(d0, d0, ss);
            d0 = qd[8]  - (double)mc.x; ss = fma(d0, d0, ss);
            d0 = qd[9]  - (double)mc.y; ss = fma(d0, d0, ss);
            d0 = qd[10] - (double)mc.z; ss = fma(d0, d0, ss);
            d0 = qd[11] - (double)mc.w; ss = fma(d0, d0, ss);
            d0 = qd[12] - (double)md.x; ss = fma(d0, d0, ss);
            d0 = qd[13] - (double)md.y; ss = fma(d0, d0, ss);
            d0 = qd[14] - (double)md.z; ss = fma(d0, d0, ss);
            d0 = qd[15] - (double)md.w; ss = fma(d0, d0, ss);
            dd8[k] = ss;
        }
    }

    // ---- exact parallel selection: rank-count over 32 refined ----
    #pragma unroll
    for (int k = 0; k < 8; ++k) ddL[qi * 33 + r * 8 + k] = dd8[k];
    __syncthreads();
    int* dst = knn_out + ((size_t)b * NPT + q0 + qi) * KNN;
    #pragma unroll
    for (int k = 0; k < 8; ++k) {
        int c = 0;
        #pragma unroll 4
        for (int j = 0; j < SIFT; ++j)
            c += (ddL[qi * 33 + j] < dd8[k]) ? 1 : 0;
        if (c < KNN) dst[c] = ms[k];
    }
}

// ------------------------------------------------- u/v GEMM: uT/vT[b][n][o]
__global__ __launch_bounds__(256) void uv_gemm(const float* __restrict__ x,
                                               const float* __restrict__ W,
                                               float* __restrict__ uT,
                                               float* __restrict__ vT) {
    __shared__ float Ax[32 * 64];
    __shared__ float Bu[32 * 68];
    __shared__ float Bv[32 * 68];

    const int b  = blockIdx.z;
    const int n0 = blockIdx.x * 64;
    const int o0 = blockIdx.y * 64;
    const int t  = threadIdx.x;
    const int tx = t & 15, ty = t >> 4;
    const float* xb = x + (size_t)b * CIN * NPT;

    float au[4][4], av_[4][4];
    #pragma unroll
    for (int i = 0; i < 4; ++i)
        #pragma unroll
        for (int j = 0; j < 4; ++j) { au[i][j] = 0.f; av_[i][j] = 0.f; }

    #pragma unroll 1
    for (int kc = 0; kc < 4; ++kc) {
        const int c0 = kc * 32;
        __syncthreads();
        #pragma unroll
        for (int e = 0; e < 2; ++e) {
            int f = e * 256 + t;
            int cz = f >> 4, ni = (f & 15) << 2;
            *(float4*)&Ax[(cz << 6) + ni] = *(const float4*)&xb[(size_t)(c0 + cz) * NPT + n0 + ni];
        }
        #pragma unroll
        for (int e = 0; e < 8; ++e) {
            int ii = e * 256 + t;
            int cz = ii & 31, oj = ii >> 5;
            float w1 = W[(size_t)(o0 + oj) * 256 + c0 + cz];
            float w2 = W[(size_t)(o0 + oj) * 256 + 128 + c0 + cz];
            Bu[cz * 68 + oj] = w1 - w2;
            Bv[cz * 68 + oj] = w2;
        }
        __syncthreads();
        #pragma unroll 8
        for (int cz = 0; cz < 32; ++cz) {
            const float4 a4 = *(const float4*)&Ax[(cz << 6) + (tx << 2)];
            float bu0 = Bu[cz * 68 + (ty << 2) + 0], bv0 = Bv[cz * 68 + (ty << 2) + 0];
            float bu1 = Bu[cz * 68 + (ty << 2) + 1], bv1 = Bv[cz * 68 + (ty << 2) + 1];
            float bu2 = Bu[cz * 68 + (ty << 2) + 2], bv2 = Bv[cz * 68 + (ty << 2) + 2];
            float bu3 = Bu[cz * 68 + (ty << 2) + 3], bv3 = Bv[cz * 68 + (ty << 2) + 3];
            au[0][0] += a4.x * bu0; au[0][1] += a4.x * bu1; au[0][2] += a4.x * bu2; au[0][3] += a4.x * bu3;
            au[1][0] += a4.y * bu0; au[1][1] += a4.y * bu1; au[1][2] += a4.y * bu2; au[1][3] += a4.y * bu3;
            au[2][0] += a4.z * bu0; au[2][1] += a4.z * bu1; au[2][2] += a4.z * bu2; au[2][3] += a4.z * bu3;
            au[3][0] += a4.w * bu0; au[3][1] += a4.w * bu1; au[3][2] += a4.w * bu2; au[3][3] += a4.w * bu3;
            av_[0][0] += a4.x * bv0; av_[0][1] += a4.x * bv1; av_[0][2] += a4.x * bv2; av_[0][3] += a4.x * bv3;
            av_[1][0] += a4.y * bv0; av_[1][1] += a4.y * bv1; av_[1][2] += a4.y * bv2; av_[1][3] += a4.y * bv3;
            av_[2][0] += a4.z * bv0; av_[2][1] += a4.z * bv1; av_[2][2] += a4.z * bv2; av_[2][3] += a4.z * bv3;
            av_[3][0] += a4.w * bv0; av_[3][1] += a4.w * bv1; av_[3][2] += a4.w * bv2; av_[3][3] += a4.w * bv3;
        }
    }
    #pragma unroll
    for (int i = 0; i < 4; ++i) {
        int n = n0 + (tx << 2) + i;
        size_t base = ((size_t)b * NPT + n) * COUT + o0 + (ty << 2);
        float4 u4 = {au[i][0], au[i][1], au[i][2], au[i][3]};
        float4 v4 = {av_[i][0], av_[i][1], av_[i][2], av_[i][3]};
        *(float4*)&uT[base] = u4;
        *(float4*)&vT[base] = v4;
    }
}

// ------------------------------------------------- fused gather+stats (pass A)
// per (b,n,o): vmax/vmin over 20 neighbors (written for out2) and BN sums via
// sum y = 20u + vsum; sum y^2 = 20u^2 + 2u*vsum + vsq.
__global__ __launch_bounds__(256) void gather_stats(const float* __restrict__ uT,
                                                    const float* __restrict__ vT,
                                                    const int* __restrict__ knn_in,
                                                    double* __restrict__ gsum,
                                                    float* __restrict__ aMax,
                                                    float* __restrict__ aMin) {
    __shared__ int sidx[64 * KNN];
    const int b  = blockIdx.y;
    const int n0 = blockIdx.x * 64;
    const int o  = threadIdx.x;
    for (int e = o; e < 64 * KNN; e += 256)
        sidx[e] = knn_in[((size_t)b * NPT + n0) * KNN + e];
    __syncthreads();
    const float* ub = uT + ((size_t)b * NPT + n0) * COUT + o;
    const float* vb = vT + (size_t)b * NPT * COUT + o;
    float* amx = aMax + ((size_t)b * NPT + n0) * COUT + o;
    float* amn = aMin + ((size_t)b * NPT + n0) * COUT + o;
    double s1 = 0.0, s2 = 0.0;
    #pragma unroll 1
    for (int s = 0; s < 64; ++s) {
        float u = ub[(size_t)s * COUT];
        float vmax = -3e38f, vmin = 3e38f, vsum = 0.f, vsq = 0.f;
        #pragma unroll
        for (int j = 0; j < KNN; ++j) {
            float v = vb[(size_t)sidx[s * KNN + j] * COUT];
            vmax = fmaxf(vmax, v);
            vmin = fminf(vmin, v);
            vsum += v;
            vsq = fmaf(v, v, vsq);
        }
        s1 += 20.0 * (double)u + (double)vsum;
        s2 += 20.0 * (double)u * (double)u + 2.0 * (double)u * (double)vsum + (double)vsq;
        amx[(size_t)s * COUT] = vmax;
        amn[(size_t)s * COUT] = vmin;
    }
    atomicAdd(&gsum[o], s1);
    atomicAdd(&gsum[COUT + o], s2);
}

// ------------------------------------------------- BN statistics (legacy pass A)
__global__ __launch_bounds__(256) void stats_kernel(const float* __restrict__ uT,
                                                    const float* __restrict__ vT,
                                                    const int* __restrict__ knn_in,
                                                    double* __restrict__ gsum) {
    __shared__ int sidx[64 * KNN];
    const int b  = blockIdx.y;
    const int n0 = blockIdx.x * 64;
    const int o  = threadIdx.x;
    for (int e = o; e < 64 * KNN; e += 256)
        sidx[e] = knn_in[((size_t)b * NPT + n0) * KNN + e];
    __syncthreads();
    const float* ub = uT + ((size_t)b * NPT + n0) * COUT + o;
    const float* vb = vT + (size_t)b * NPT * COUT + o;
    double s1 = 0.0, s2 = 0.0;
    #pragma unroll 1
    for (int s = 0; s < 64; ++s) {
        float u = ub[(size_t)s * COUT];
        #pragma unroll
        for (int j = 0; j < KNN; ++j) {
            float y = u + vb[(size_t)sidx[s * KNN + j] * COUT];
            s1 += (double)y;
            s2 = fma((double)y, (double)y, s2);
        }
    }
    atomicAdd(&gsum[o], s1);
    atomicAdd(&gsum[COUT + o], s2);
}

// ------------------------------------------------- fold stats -> scale/shift
__global__ void finalize_kernel(const double* __restrict__ gsum,
                                const float* __restrict__ gamma,
                                const float* __restrict__ beta,
                                float* __restrict__ st) {
    const int o = threadIdx.x;
    const double M = (double)B_ * NPT * KNN;
    double mean = gsum[o] / M;
    double var  = gsum[COUT + o] / M - mean * mean;
    float inv = 1.0f / sqrtf((float)var + EPS);
    float s = gamma[o] * inv;
    st[o] = s;
    st[COUT + o] = beta[o] - (float)mean * s;
}

// ------------------------------------------------- out from u/vmax/vmin (fused)
__global__ __launch_bounds__(256, 2) void out2_kernel(const float* __restrict__ uT,
                                                      const float* __restrict__ aMax,
                                                      const float* __restrict__ aMin,
                                                      const float* __restrict__ st,
                                                      float* __restrict__ out) {
    __shared__ float zt[256 * 68];
    const int b  = blockIdx.y;
    const int n0 = blockIdx.x * 64;
    const int o  = threadIdx.x;
    const float s  = st[o];
    const float tt = st[COUT + o];
    const float* ub  = uT   + ((size_t)b * NPT + n0) * COUT + o;
    const float* amx = aMax + ((size_t)b * NPT + n0) * COUT + o;
    const float* amn = aMin + ((size_t)b * NPT + n0) * COUT + o;
    #pragma unroll 2
    for (int si = 0; si < 64; ++si) {
        float u = ub[(size_t)si * COUT];
        float y1 = u + amx[(size_t)si * COUT];     // == max_j (u+v_j), RN monotone
        float y2 = u + amn[(size_t)si * COUT];
        float z1 = fmaxf(s * y1 + tt, 0.f);
        float z2 = fmaxf(s * y2 + tt, 0.f);
        zt[o * 68 + si] = fmaxf(z1, z2);
    }
    __syncthreads();
    float* dst = out + ((size_t)b * COUT + o) * NPT + n0;
    #pragma unroll
    for (int i = 0; i < 16; ++i)
        *(float4*)&dst[i * 4] = *(const float4*)&zt[o * 68 + i * 4];
}

// ------------------------------------------------- legacy gather+affine+relu+max
__global__ __launch_bounds__(256, 2) void out_kernel(const float* __restrict__ uT,
                                                     const float* __restrict__ vT,
                                                     const int* __restrict__ knn_in,
                                                     const float* __restrict__ st,
                                                     float* __restrict__ out) {
    __shared__ int sidx[64 * KNN];
    __shared__ float zt[256 * 68];
    const int b  = blockIdx.y;
    const int n0 = blockIdx.x * 64;
    const int o  = threadIdx.x;
    for (int e = o; e < 64 * KNN; e += 256)
        sidx[e] = knn_in[((size_t)b * NPT + n0) * KNN + e];
    __syncthreads();
    const float s  = st[o];
    const float tt = st[COUT + o];
    const float* ub = uT + ((size_t)b * NPT + n0) * COUT + o;
    const float* vb = vT + (size_t)b * NPT * COUT + o;
    #pragma unroll 1
    for (int si = 0; si < 64; ++si) {
        float u = ub[(size_t)si * COUT];
        float ymax = -3e38f, ymin = 3e38f;
        #pragma unroll
        for (int j = 0; j < KNN; ++j) {
            float y = u + vb[(size_t)sidx[si * KNN + j] * COUT];
            ymax = fmaxf(ymax, y);
            ymin = fminf(ymin, y);
        }
        float z1 = fmaxf(s * ymax + tt, 0.f);
        float z2 = fmaxf(s * ymin + tt, 0.f);
        zt[o * 68 + si] = fmaxf(z1, z2);
    }
    __syncthreads();
    float* dst = out + ((size_t)b * COUT + o) * NPT + n0;
    #pragma unroll
    for (int i = 0; i < 16; ++i)
        *(float4*)&dst[i * 4] = *(const float4*)&zt[o * 68 + i * 4];
}

extern "C" void kernel_launch(void* const* d_in, const int* in_sizes, int n_in,
                              void* d_out, int out_size, void* d_ws, size_t ws_size,
                              hipStream_t stream) {
    const float* x     = (const float*)d_in[0];
    const float* W     = (const float*)d_in[1];
    const float* gamma = (const float*)d_in[2];
    const float* beta  = (const float*)d_in[3];
    float* out = (float*)d_out;
    char* ws = (char*)d_ws;
    float*     sqh  = (float*)(ws + SQ_OFF);
    int*       idx  = (int*)(ws + IDX_OFF);
    float*     xT   = (float*)(ws + XT_OFF);    // aliases uT
    _Float16*  xhT  = (_Float16*)(ws + XHT_OFF);// aliases vT
    float*     uT   = (float*)(ws + UT_OFF);
    float*     vT   = (float*)(ws + VT_OFF);
    double*    gsum = (double*)(ws + GS_OFF);
    float*     st   = (float*)(ws + ST_OFF);
    float*     aMax = (float*)(ws + AMAX_OFF);
    float*     aMin = (float*)(ws + AMIN_OFF);
    const bool fused = (ws_size >= WS_NEED_FUSED);

    hipMemsetAsync(gsum, 0, 2 * COUT * sizeof(double), stream);
    prep_kernel<<<dim3(32, 16), 256, 0, stream>>>(x, xT, xhT, sqh);
    knn_kernel<<<dim3(32, 16), 256, 0, stream>>>(xhT, xT, sqh, idx);
    // uv_gemm AFTER knn: uT/vT regions alias xT/xhT
    uv_gemm<<<dim3(32, 4, 16), 256, 0, stream>>>(x, W, uT, vT);
    if (fused) {
        gather_stats<<<dim3(32, 16), 256, 0, stream>>>(uT, vT, idx, gsum, aMax, aMin);
        finalize_kernel<<<1, 256, 0, stream>>>(gsum, gamma, beta, st);
        out2_kernel<<<dim3(32, 16), 256, 0, stream>>>(uT, aMax, aMin, st, out);
    } else {
        stats_kernel<<<dim3(32, 16), 256, 0, stream>>>(uT, vT, idx, gsum);
        finalize_kernel<<<1, 256, 0, stream>>>(gsum, gamma, beta, st);
        out_kernel<<<dim3(32, 16), 256, 0, stream>>>(uT, vT, idx, st, out);
    }
}

// Round 9
// 370.937 us; speedup vs baseline: 2.9074x; 1.1034x over previous
//
#include <hip/hip_runtime.h>

#define B_   16
#define CIN  128
#define NPT  2048
#define COUT 256
#define KNN  20
#define KEEP 16
#define CAND 64
#define SIFT 32
#define EPS  1e-5f
#define DBIAS 256.0f   // must exceed max_q |x_q|^2 (chi2_128 max ~210 over 32k)

// workspace byte offsets
#define SQ_OFF   0ull                          // sqh: 32768 f (fp16-rounded |x|^2)
#define IDX_OFF  131072ull                     // 16*2048*20 i32
#define UT_OFF   2752512ull                    // 16*2048*256 f
#define VT_OFF   36306944ull                   // 16*2048*256 f
#define GS_OFF   69861376ull                   // 2*256 double
#define ST_OFF   69865472ull                   // 2*256 f
// fused-path buffers (only when ws_size is large enough)
#define AMAX_OFF 69871616ull                   // 16*2048*256 f = 33554432
#define AMIN_OFF 103426048ull                  // 16*2048*256 f
#define WS_NEED_FUSED 136980480ull
// Fused mode: xT/xhT/Wu/Wv live in the AMAX region (dead until gather_stats
// writes aMax): xT 16.8M + xhT 8.4M + Wu 64K + Wv 64K = 25.3M < 33.5M.
// Fallback mode: xT aliases uT, xhT aliases vT (uv_gemm fp32 runs after knn).
#define XT_OFF   UT_OFF
#define XHT_OFF  VT_OFF

typedef _Float16 f16x8 __attribute__((ext_vector_type(8)));
typedef float    f32x4 __attribute__((ext_vector_type(4)));

// ---------------------------------------------------- prep: xT, xhT, sqh
__global__ __launch_bounds__(256) void prep_kernel(const float* __restrict__ x,
                                                   float* __restrict__ xT,
                                                   _Float16* __restrict__ xhT,
                                                   float* __restrict__ sqh) {
    __shared__ float Ls[128 * 68];
    __shared__ float ps[4 * 64];
    const int b = blockIdx.y, n0 = blockIdx.x * 64, t = threadIdx.x;
    const float* xb = x + (size_t)b * CIN * NPT;
    #pragma unroll
    for (int e = 0; e < 8; ++e) {              // 2048 float4 loads, coalesced
        int f = e * 256 + t;
        int c = f >> 4, n4 = (f & 15) << 2;
        *(float4*)&Ls[c * 68 + n4] = *(const float4*)&xb[(size_t)c * NPT + n0 + n4];
    }
    __syncthreads();
    {                                          // sq partials on fp16-rounded vals
        int nl = t & 63, part = t >> 6;
        float acc = 0.f;
        #pragma unroll
        for (int j = 0; j < 32; ++j) {
            float vh = (float)(_Float16)Ls[(part * 32 + j) * 68 + nl];
            acc += vh * vh;
        }
        ps[part * 64 + nl] = acc;
    }
    #pragma unroll
    for (int e = 0; e < 2; ++e) {              // transpose writes: (nl, 16-c chunk)
        int u = e * 256 + t;
        int nl = u >> 3, ck = (u & 7) << 4;
        float vv[16];
        #pragma unroll
        for (int j = 0; j < 16; ++j) vv[j] = Ls[(ck + j) * 68 + nl];
        size_t row = (size_t)b * NPT + n0 + nl;
        #pragma unroll
        for (int j = 0; j < 4; ++j) {
            float4 w = {vv[4 * j], vv[4 * j + 1], vv[4 * j + 2], vv[4 * j + 3]};
            *(float4*)&xT[row * CIN + ck + 4 * j] = w;
        }
        f16x8 h0, h1;
        #pragma unroll
        for (int j = 0; j < 8; ++j) { h0[j] = (_Float16)vv[j]; h1[j] = (_Float16)vv[8 + j]; }
        *(f16x8*)&xhT[row * CIN + ck] = h0;
        *(f16x8*)&xhT[row * CIN + ck + 8] = h1;
    }
    __syncthreads();
    if (t < 64) sqh[b * NPT + n0 + t] = ps[t] + ps[64 + t] + ps[128 + t] + ps[192 + t];
}

// ---------------------------------------------------- W -> fp16 Wu/Wv
__global__ void wconv_kernel(const float* __restrict__ W,
                             _Float16* __restrict__ Wu,
                             _Float16* __restrict__ Wv) {
    int gid = blockIdx.x * 256 + threadIdx.x;      // 32768 = 256 o x 128 c
    int o = gid >> 7, c = gid & 127;
    float w1 = W[o * 256 + c], w2 = W[o * 256 + 128 + c];
    Wu[gid] = (_Float16)(w1 - w2);
    Wv[gid] = (_Float16)w2;
}

// -------------------------------------------- fragment staging via DMA
__device__ __forceinline__ void stage_pts(const _Float16* __restrict__ xhb,
                                          _Float16* buf, int base_n, int t) {
    const int l15 = t & 15, ks = t >> 6;
    const int quad = (t >> 4) & 3;
    const int c = ks * 32 + quad * 8;
    #pragma unroll
    for (int e = 0; e < 4; ++e) {
        const int n = base_n + e * 16 + l15;
        const _Float16* src = xhb + (size_t)n * CIN + c;
        _Float16* dst = buf + (size_t)(e * 256 + (t & 192)) * 8;   // wave-uniform base
        __builtin_amdgcn_global_load_lds(
            (const __attribute__((address_space(1))) void*)src,
            (__attribute__((address_space(3))) void*)dst, 16, 0, 0);
    }
}

// ---------------------------------------------------------------- KNN
// fp16 MFMA distance tiles + per-lane top-16 (med3 pair-insert chain on
// packed positive keys: 21-bit chopped distance | 11-bit FULL m -> globally
// unique keys) + quantized pre-sift to 32/query + fp64 refinement
// (8 rows/lane) + parallel rank-count -> exact top-20 set.
__global__ __launch_bounds__(256, 2) void knn_kernel(const _Float16* __restrict__ xhT,
                                                     const float* __restrict__ xT,
                                                     const float* __restrict__ sqh,
                                                     int* __restrict__ knn_out) {
    __shared__ char smraw[58368];
    _Float16* bufA = (_Float16*)smraw;              // 16 KB: A frags, then B dbuf
    _Float16* bufB = (_Float16*)(smraw + 16384);    // 16 KB: B frags
    float*    Dt   = (float*)(smraw + 32768);       // 64 x 68 f
    float*    sqm  = (float*)(smraw + 50176);       // 2048 f (biased +DBIAS)

    const int b  = blockIdx.y;
    const int q0 = blockIdx.x * 64;
    const int t  = threadIdx.x;
    const int lane = t & 63, wv = t >> 6;
    const int l15 = lane & 15, quad = lane >> 4;
    const _Float16* xhb = xhT + (size_t)b * NPT * CIN;

    // Dt[q][m] = |xm|^2 + DBIAS - 2<q,m>  (drops |xq|^2: constant per query).
    // DBIAS > max |xq|^2 keeps Dt > 0 so float bit order == value order.
    #pragma unroll
    for (int e = 0; e < 8; ++e)
        sqm[e * 256 + t] = sqh[b * NPT + e * 256 + t] + DBIAS;

    stage_pts(xhb, bufA, q0, t);                    // A fragments (64 queries)
    __syncthreads();
    f16x8 af[4];
    #pragma unroll
    for (int ks = 0; ks < 4; ++ks)
        af[ks] = *(const f16x8*)(bufA + (size_t)((wv * 4 + ks) * 64 + lane) * 8);
    stage_pts(xhb, bufB, 0, t);                     // B stage 0

    float bd[KEEP];
    #pragma unroll
    for (int i = 0; i < KEEP; ++i) bd[i] = 3.0e38f;
    const int qi = t >> 2, r = t & 3;

    #pragma unroll 1
    for (int s = 0; s < 32; ++s) {
        __syncthreads();                            // buf[s&1] ready; Dt consumed
        _Float16* cur = (s & 1) ? bufA : bufB;
        if (s < 31) stage_pts(xhb, (s & 1) ? bufB : bufA, (s + 1) * 64, t);
        const int m0 = s * 64;
        f32x4 acc[4];
        #pragma unroll
        for (int mt4 = 0; mt4 < 4; ++mt4) acc[mt4] = (f32x4){0.f, 0.f, 0.f, 0.f};
        #pragma unroll
        for (int ks = 0; ks < 4; ++ks) {
            #pragma unroll
            for (int mt4 = 0; mt4 < 4; ++mt4) {
                f16x8 bf = *(const f16x8*)(cur + (size_t)((mt4 * 4 + ks) * 64 + lane) * 8);
                acc[mt4] = __builtin_amdgcn_mfma_f32_16x16x32_f16(af[ks], bf, acc[mt4], 0, 0, 0);
            }
        }
        #pragma unroll
        for (int mt4 = 0; mt4 < 4; ++mt4) {
            float sm_ = sqm[m0 + mt4 * 16 + l15];   // = |xm|^2 + DBIAS
            #pragma unroll
            for (int reg = 0; reg < 4; ++reg) {     // D row = q (A free dim)
                int q = wv * 16 + quad * 4 + reg;
                Dt[q * 68 + mt4 * 16 + l15] = sm_ - 2.f * acc[mt4][reg];
            }
        }
        __syncthreads();                            // Dt(s) visible
        // per-lane top-16 over subset m%4==r: pair-insert via min/med3/max.
        #pragma unroll
        for (int p = 0; p < 8; ++p) {
            int i2a = p * 2, i2b = p * 2 + 1;
            unsigned ba = __float_as_uint(Dt[qi * 68 + (i2a << 2) + r]);
            unsigned bb = __float_as_uint(Dt[qi * 68 + (i2b << 2) + r]);
            float k0 = __uint_as_float((ba & 0xFFFFF800u) | (unsigned)(m0 + (i2a << 2) + r));
            float k1 = __uint_as_float((bb & 0xFFFFF800u) | (unsigned)(m0 + (i2b << 2) + r));
            float lo = fminf(k0, k1), hi = fmaxf(k0, k1);
            #pragma unroll
            for (int sl = 0; sl < KEEP; ++sl) {
                float bv = bd[sl];
                bd[sl] = fminf(bv, lo);
                float med = __builtin_amdgcn_fmed3f(bv, lo, hi);  // lo<=hi
                hi = fmaxf(bv, hi);
                lo = med;
            }
        }
    }

    // ---- quantized pre-sift: rank-count the 64 packed keys per query ----
    float* Keys = (float*)smraw;                   // [64][65] f = 16640 B
    int*   Surv = (int*)(smraw + 16640);           // [64][33] i = 8448 B
    double* ddL = (double*)(smraw + 25088);        // [64][33] d = 16896 B
    #pragma unroll
    for (int i = 0; i < KEEP; ++i)
        Keys[qi * 65 + r * KEEP + i] = bd[i];
    __syncthreads();
    {
        int cnt[KEEP];
        #pragma unroll
        for (int i = 0; i < KEEP; ++i) cnt[i] = 0;
        #pragma unroll 4
        for (int j = 0; j < CAND; ++j) {
            float kj = Keys[qi * 65 + j];
            #pragma unroll
            for (int i = 0; i < KEEP; ++i)
                cnt[i] += (kj < bd[i]) ? 1 : 0;
        }
        __syncthreads();                           // Keys consumed; Surv region free
        #pragma unroll
        for (int i = 0; i < KEEP; ++i)
            if (cnt[i] < SIFT)
                Surv[qi * 33 + cnt[i]] = (int)(__float_as_uint(bd[i]) & 0x7FFu);
    }
    __syncthreads();

    // ---- fp64 refinement of 8 survivors per lane (exact vs numpy) ----
    int ms[8];
    #pragma unroll
    for (int k = 0; k < 8; ++k) ms[k] = Surv[qi * 33 + r * 8 + k] & 2047;
    double dd8[8];
    #pragma unroll
    for (int k = 0; k < 8; ++k) dd8[k] = 0.0;
    const float* xTb = xT + (size_t)b * NPT * CIN;
    const float* qrow = xTb + (size_t)(q0 + qi) * CIN;
    #pragma unroll 1
    for (int ch = 0; ch < 8; ++ch) {
        double qd[16];
        #pragma unroll
        for (int j = 0; j < 4; ++j) {
            float4 qv = *(const float4*)&qrow[ch * 16 + 4 * j];
            qd[4 * j] = (double)qv.x; qd[4 * j + 1] = (double)qv.y;
            qd[4 * j + 2] = (double)qv.z; qd[4 * j + 3] = (double)qv.w;
        }
        #pragma unroll
        for (int k = 0; k < 8; ++k) {
            const float* mrow = xTb + (size_t)ms[k] * CIN + ch * 16;
            float4 ma = *(const float4*)&mrow[0];
            float4 mb = *(const float4*)&mrow[4];
            float4 mc = *(const float4*)&mrow[8];
            float4 md = *(const float4*)&mrow[12];
            double ss = dd8[k], d0;
            d0 = qd[0]  - (double)ma.x; ss = fma(d0, d0, ss);
            d0 = qd[1]  - (double)ma.y; ss = fma(d0, d0, ss);
            d0 = qd[2]  - (double)ma.z; ss = fma(d0, d0, ss);
            d0 = qd[3]  - (double)ma.w; ss = fma(d0, d0, ss);
            d0 = qd[4]  - (double)mb.x; ss = fma(d0, d0, ss);
            d0 = qd[5]  - (double)mb.y; ss = fma(d0, d0, ss);
            d0 = qd[6]  - (double)mb.z; ss = fma(d0, d0, ss);
            d0 = qd[7]  - (double)mb.w; ss = fma(d0, d0, ss);
            d0 = qd[8]  - (double)mc.x; ss = fma(d0, d0, ss);
            d0 = qd[9]  - (double)mc.y; ss = fma(d0, d0, ss);
            d0 = qd[10] - (double)mc.z; ss = fma(d0, d0, ss);
            d0 = qd[11] - (double)mc.w; ss = fma(d0, d0, ss);
            d0 = qd[12] - (double)md.x; ss = fma(d0, d0, ss);
            d0 = qd[13] - (double)md.y; ss = fma(d0, d0, ss);
            d0 = qd[14] - (double)md.z; ss = fma(d0, d0, ss);
            d0 = qd[15] - (double)md.w; ss = fma(d0, d0, ss);
            dd8[k] = ss;
        }
    }

    // ---- exact parallel selection: rank-count over 32 refined ----
    #pragma unroll
    for (int k = 0; k < 8; ++k) ddL[qi * 33 + r * 8 + k] = dd8[k];
    __syncthreads();
    int* dst = knn_out + ((size_t)b * NPT + q0 + qi) * KNN;
    #pragma unroll
    for (int k = 0; k < 8; ++k) {
        int c = 0;
        #pragma unroll 4
        for (int j = 0; j < SIFT; ++j)
            c += (ddL[qi * 33 + j] < dd8[k]) ? 1 : 0;
        if (c < KNN) dst[c] = ms[k];
    }
}

// ------------------------------------------------- u/v GEMM via fp16 MFMA
// A = Wu/Wv fragments (o rows), B = xh fragments (n cols), D[row=o][col=n].
// Lane (l15,quad) holds 4 consecutive o for n=l15 -> direct float4 store.
__global__ __launch_bounds__(256) void uv_gemm_h(const _Float16* __restrict__ xhT,
                                                 const _Float16* __restrict__ Wu,
                                                 const _Float16* __restrict__ Wv,
                                                 float* __restrict__ uT,
                                                 float* __restrict__ vT) {
    __shared__ _Float16 Bx[8192];                  // 64 n x 128 c, fragment order
    const int b = blockIdx.y, n0 = blockIdx.x * 64, t = threadIdx.x;
    const int lane = t & 63, w = t >> 6, l15 = lane & 15, quad = lane >> 4;
    stage_pts(xhT + (size_t)b * NPT * CIN, Bx, n0, t);
    __syncthreads();
    f16x8 bf[4];
    #pragma unroll
    for (int ks = 0; ks < 4; ++ks)
        bf[ks] = *(const f16x8*)(Bx + (size_t)((w * 4 + ks) * 64 + lane) * 8);
    const int n = n0 + w * 16 + l15;
    #pragma unroll 1
    for (int ot = 0; ot < 16; ++ot) {
        const _Float16* wu = Wu + (size_t)(ot * 16 + l15) * 128 + quad * 8;
        const _Float16* wv2 = Wv + (size_t)(ot * 16 + l15) * 128 + quad * 8;
        f32x4 au = (f32x4){0.f, 0.f, 0.f, 0.f};
        f32x4 av = (f32x4){0.f, 0.f, 0.f, 0.f};
        #pragma unroll
        for (int ks = 0; ks < 4; ++ks) {
            f16x8 a_u = *(const f16x8*)(wu + ks * 32);
            f16x8 a_v = *(const f16x8*)(wv2 + ks * 32);
            au = __builtin_amdgcn_mfma_f32_16x16x32_f16(a_u, bf[ks], au, 0, 0, 0);
            av = __builtin_amdgcn_mfma_f32_16x16x32_f16(a_v, bf[ks], av, 0, 0, 0);
        }
        size_t base = ((size_t)b * NPT + n) * COUT + ot * 16 + quad * 4;
        *(f32x4*)&uT[base] = au;
        *(f32x4*)&vT[base] = av;
    }
}

// ------------------------------------------------- legacy fp32 u/v GEMM (fallback)
__global__ __launch_bounds__(256) void uv_gemm(const float* __restrict__ x,
                                               const float* __restrict__ W,
                                               float* __restrict__ uT,
                                               float* __restrict__ vT) {
    __shared__ float Ax[32 * 64];
    __shared__ float Bu[32 * 68];
    __shared__ float Bv[32 * 68];
    const int b  = blockIdx.z;
    const int n0 = blockIdx.x * 64;
    const int o0 = blockIdx.y * 64;
    const int t  = threadIdx.x;
    const int tx = t & 15, ty = t >> 4;
    const float* xb = x + (size_t)b * CIN * NPT;
    float au[4][4], av_[4][4];
    #pragma unroll
    for (int i = 0; i < 4; ++i)
        #pragma unroll
        for (int j = 0; j < 4; ++j) { au[i][j] = 0.f; av_[i][j] = 0.f; }
    #pragma unroll 1
    for (int kc = 0; kc < 4; ++kc) {
        const int c0 = kc * 32;
        __syncthreads();
        #pragma unroll
        for (int e = 0; e < 2; ++e) {
            int f = e * 256 + t;
            int cz = f >> 4, ni = (f & 15) << 2;
            *(float4*)&Ax[(cz << 6) + ni] = *(const float4*)&xb[(size_t)(c0 + cz) * NPT + n0 + ni];
        }
        #pragma unroll
        for (int e = 0; e < 8; ++e) {
            int ii = e * 256 + t;
            int cz = ii & 31, oj = ii >> 5;
            float w1 = W[(size_t)(o0 + oj) * 256 + c0 + cz];
            float w2 = W[(size_t)(o0 + oj) * 256 + 128 + c0 + cz];
            Bu[cz * 68 + oj] = w1 - w2;
            Bv[cz * 68 + oj] = w2;
        }
        __syncthreads();
        #pragma unroll 8
        for (int cz = 0; cz < 32; ++cz) {
            const float4 a4 = *(const float4*)&Ax[(cz << 6) + (tx << 2)];
            float bu0 = Bu[cz * 68 + (ty << 2) + 0], bv0 = Bv[cz * 68 + (ty << 2) + 0];
            float bu1 = Bu[cz * 68 + (ty << 2) + 1], bv1 = Bv[cz * 68 + (ty << 2) + 1];
            float bu2 = Bu[cz * 68 + (ty << 2) + 2], bv2 = Bv[cz * 68 + (ty << 2) + 2];
            float bu3 = Bu[cz * 68 + (ty << 2) + 3], bv3 = Bv[cz * 68 + (ty << 2) + 3];
            au[0][0] += a4.x * bu0; au[0][1] += a4.x * bu1; au[0][2] += a4.x * bu2; au[0][3] += a4.x * bu3;
            au[1][0] += a4.y * bu0; au[1][1] += a4.y * bu1; au[1][2] += a4.y * bu2; au[1][3] += a4.y * bu3;
            au[2][0] += a4.z * bu0; au[2][1] += a4.z * bu1; au[2][2] += a4.z * bu2; au[2][3] += a4.z * bu3;
            au[3][0] += a4.w * bu0; au[3][1] += a4.w * bu1; au[3][2] += a4.w * bu2; au[3][3] += a4.w * bu3;
            av_[0][0] += a4.x * bv0; av_[0][1] += a4.x * bv1; av_[0][2] += a4.x * bv2; av_[0][3] += a4.x * bv3;
            av_[1][0] += a4.y * bv0; av_[1][1] += a4.y * bv1; av_[1][2] += a4.y * bv2; av_[1][3] += a4.y * bv3;
            av_[2][0] += a4.z * bv0; av_[2][1] += a4.z * bv1; av_[2][2] += a4.z * bv2; av_[2][3] += a4.z * bv3;
            av_[3][0] += a4.w * bv0; av_[3][1] += a4.w * bv1; av_[3][2] += a4.w * bv2; av_[3][3] += a4.w * bv3;
        }
    }
    #pragma unroll
    for (int i = 0; i < 4; ++i) {
        int n = n0 + (tx << 2) + i;
        size_t base = ((size_t)b * NPT + n) * COUT + o0 + (ty << 2);
        float4 u4 = {au[i][0], au[i][1], au[i][2], au[i][3]};
        float4 v4 = {av_[i][0], av_[i][1], av_[i][2], av_[i][3]};
        *(float4*)&uT[base] = u4;
        *(float4*)&vT[base] = v4;
    }
}

// ------------------------------------------------- fused gather+stats (pass A)
// n-split x4 for latency hiding. Per (b,n,o): vmax/vmin (for out2) + BN sums
// via sum y = 20u + vsum; sum y^2 = 20u^2 + 2u*vsum + vsq.
__global__ __launch_bounds__(256) void gather_stats(const float* __restrict__ uT,
                                                    const float* __restrict__ vT,
                                                    const int* __restrict__ knn_in,
                                                    double* __restrict__ gsum,
                                                    float* __restrict__ aMax,
                                                    float* __restrict__ aMin) {
    __shared__ int sidx[16 * KNN];
    const int b  = blockIdx.y;
    const int n0 = blockIdx.x * 64 + blockIdx.z * 16;
    const int o  = threadIdx.x;
    for (int e = o; e < 16 * KNN; e += 256)
        sidx[e] = knn_in[((size_t)b * NPT + n0) * KNN + e];
    __syncthreads();
    const float* ub = uT + ((size_t)b * NPT + n0) * COUT + o;
    const float* vb = vT + (size_t)b * NPT * COUT + o;
    float* amx = aMax + ((size_t)b * NPT + n0) * COUT + o;
    float* amn = aMin + ((size_t)b * NPT + n0) * COUT + o;
    double s1 = 0.0, s2 = 0.0;
    #pragma unroll 1
    for (int s = 0; s < 16; ++s) {
        float u = ub[(size_t)s * COUT];
        float vmax = -3e38f, vmin = 3e38f, vsum = 0.f, vsq = 0.f;
        #pragma unroll
        for (int j = 0; j < KNN; ++j) {
            float v = vb[(size_t)sidx[s * KNN + j] * COUT];
            vmax = fmaxf(vmax, v);
            vmin = fminf(vmin, v);
            vsum += v;
            vsq = fmaf(v, v, vsq);
        }
        s1 += 20.0 * (double)u + (double)vsum;
        s2 += 20.0 * (double)u * (double)u + 2.0 * (double)u * (double)vsum + (double)vsq;
        amx[(size_t)s * COUT] = vmax;
        amn[(size_t)s * COUT] = vmin;
    }
    atomicAdd(&gsum[o], s1);
    atomicAdd(&gsum[COUT + o], s2);
}

// ------------------------------------------------- BN statistics (legacy pass A)
__global__ __launch_bounds__(256) void stats_kernel(const float* __restrict__ uT,
                                                    const float* __restrict__ vT,
                                                    const int* __restrict__ knn_in,
                                                    double* __restrict__ gsum) {
    __shared__ int sidx[64 * KNN];
    const int b  = blockIdx.y;
    const int n0 = blockIdx.x * 64;
    const int o  = threadIdx.x;
    for (int e = o; e < 64 * KNN; e += 256)
        sidx[e] = knn_in[((size_t)b * NPT + n0) * KNN + e];
    __syncthreads();
    const float* ub = uT + ((size_t)b * NPT + n0) * COUT + o;
    const float* vb = vT + (size_t)b * NPT * COUT + o;
    double s1 = 0.0, s2 = 0.0;
    #pragma unroll 1
    for (int s = 0; s < 64; ++s) {
        float u = ub[(size_t)s * COUT];
        #pragma unroll
        for (int j = 0; j < KNN; ++j) {
            float y = u + vb[(size_t)sidx[s * KNN + j] * COUT];
            s1 += (double)y;
            s2 = fma((double)y, (double)y, s2);
        }
    }
    atomicAdd(&gsum[o], s1);
    atomicAdd(&gsum[COUT + o], s2);
}

// ------------------------------------------------- fold stats -> scale/shift
__global__ void finalize_kernel(const double* __restrict__ gsum,
                                const float* __restrict__ gamma,
                                const float* __restrict__ beta,
                                float* __restrict__ st) {
    const int o = threadIdx.x;
    const double M = (double)B_ * NPT * KNN;
    double mean = gsum[o] / M;
    double var  = gsum[COUT + o] / M - mean * mean;
    float inv = 1.0f / sqrtf((float)var + EPS);
    float s = gamma[o] * inv;
    st[o] = s;
    st[COUT + o] = beta[o] - (float)mean * s;
}

// ------------------------------------------------- out from u/vmax/vmin (fused)
__global__ __launch_bounds__(256, 2) void out2_kernel(const float* __restrict__ uT,
                                                      const float* __restrict__ aMax,
                                                      const float* __restrict__ aMin,
                                                      const float* __restrict__ st,
                                                      float* __restrict__ out) {
    __shared__ float zt[256 * 68];
    const int b  = blockIdx.y;
    const int n0 = blockIdx.x * 64;
    const int o  = threadIdx.x;
    const float s  = st[o];
    const float tt = st[COUT + o];
    const float* ub  = uT   + ((size_t)b * NPT + n0) * COUT + o;
    const float* amx = aMax + ((size_t)b * NPT + n0) * COUT + o;
    const float* amn = aMin + ((size_t)b * NPT + n0) * COUT + o;
    #pragma unroll 2
    for (int si = 0; si < 64; ++si) {
        float u = ub[(size_t)si * COUT];
        float y1 = u + amx[(size_t)si * COUT];     // == max_j (u+v_j), RN monotone
        float y2 = u + amn[(size_t)si * COUT];
        float z1 = fmaxf(s * y1 + tt, 0.f);
        float z2 = fmaxf(s * y2 + tt, 0.f);
        zt[o * 68 + si] = fmaxf(z1, z2);
    }
    __syncthreads();
    float* dst = out + ((size_t)b * COUT + o) * NPT + n0;
    #pragma unroll
    for (int i = 0; i < 16; ++i)
        *(float4*)&dst[i * 4] = *(const float4*)&zt[o * 68 + i * 4];
}

// ------------------------------------------------- legacy gather+affine+relu+max
__global__ __launch_bounds__(256, 2) void out_kernel(const float* __restrict__ uT,
                                                     const float* __restrict__ vT,
                                                     const int* __restrict__ knn_in,
                                                     const float* __restrict__ st,
                                                     float* __restrict__ out) {
    __shared__ int sidx[64 * KNN];
    __shared__ float zt[256 * 68];
    const int b  = blockIdx.y;
    const int n0 = blockIdx.x * 64;
    const int o  = threadIdx.x;
    for (int e = o; e < 64 * KNN; e += 256)
        sidx[e] = knn_in[((size_t)b * NPT + n0) * KNN + e];
    __syncthreads();
    const float s  = st[o];
    const float tt = st[COUT + o];
    const float* ub = uT + ((size_t)b * NPT + n0) * COUT + o;
    const float* vb = vT + (size_t)b * NPT * COUT + o;
    #pragma unroll 1
    for (int si = 0; si < 64; ++si) {
        float u = ub[(size_t)si * COUT];
        float ymax = -3e38f, ymin = 3e38f;
        #pragma unroll
        for (int j = 0; j < KNN; ++j) {
            float y = u + vb[(size_t)sidx[si * KNN + j] * COUT];
            ymax = fmaxf(ymax, y);
            ymin = fminf(ymin, y);
        }
        float z1 = fmaxf(s * ymax + tt, 0.f);
        float z2 = fmaxf(s * ymin + tt, 0.f);
        zt[o * 68 + si] = fmaxf(z1, z2);
    }
    __syncthreads();
    float* dst = out + ((size_t)b * COUT + o) * NPT + n0;
    #pragma unroll
    for (int i = 0; i < 16; ++i)
        *(float4*)&dst[i * 4] = *(const float4*)&zt[o * 68 + i * 4];
}

extern "C" void kernel_launch(void* const* d_in, const int* in_sizes, int n_in,
                              void* d_out, int out_size, void* d_ws, size_t ws_size,
                              hipStream_t stream) {
    const float* x     = (const float*)d_in[0];
    const float* W     = (const float*)d_in[1];
    const float* gamma = (const float*)d_in[2];
    const float* beta  = (const float*)d_in[3];
    float* out = (float*)d_out;
    char* ws = (char*)d_ws;
    float*     sqh  = (float*)(ws + SQ_OFF);
    int*       idx  = (int*)(ws + IDX_OFF);
    float*     uT   = (float*)(ws + UT_OFF);
    float*     vT   = (float*)(ws + VT_OFF);
    double*    gsum = (double*)(ws + GS_OFF);
    float*     st   = (float*)(ws + ST_OFF);
    float*     aMax = (float*)(ws + AMAX_OFF);
    float*     aMin = (float*)(ws + AMIN_OFF);
    const bool fused = (ws_size >= WS_NEED_FUSED);

    hipMemsetAsync(gsum, 0, 2 * COUT * sizeof(double), stream);
    if (fused) {
        // xT/xhT/Wu/Wv in the aMax region (dead until gather_stats)
        float*    xT  = (float*)(ws + AMAX_OFF);
        _Float16* xhT = (_Float16*)(ws + AMAX_OFF + 16777216ull);
        _Float16* Wu  = (_Float16*)(ws + AMAX_OFF + 25165824ull);
        _Float16* Wv  = (_Float16*)(ws + AMAX_OFF + 25231360ull);
        prep_kernel<<<dim3(32, 16), 256, 0, stream>>>(x, xT, xhT, sqh);
        wconv_kernel<<<128, 256, 0, stream>>>(W, Wu, Wv);
        knn_kernel<<<dim3(32, 16), 256, 0, stream>>>(xhT, xT, sqh, idx);
        uv_gemm_h<<<dim3(32, 16), 256, 0, stream>>>(xhT, Wu, Wv, uT, vT);
        gather_stats<<<dim3(32, 16, 4), 256, 0, stream>>>(uT, vT, idx, gsum, aMax, aMin);
        finalize_kernel<<<1, 256, 0, stream>>>(gsum, gamma, beta, st);
        out2_kernel<<<dim3(32, 16), 256, 0, stream>>>(uT, aMax, aMin, st, out);
    } else {
        // fallback: xT aliases uT, xhT aliases vT; fp32 uv after knn
        float*    xT  = (float*)(ws + XT_OFF);
        _Float16* xhT = (_Float16*)(ws + XHT_OFF);
        prep_kernel<<<dim3(32, 16), 256, 0, stream>>>(x, xT, xhT, sqh);
        knn_kernel<<<dim3(32, 16), 256, 0, stream>>>(xhT, xT, sqh, idx);
        uv_gemm<<<dim3(32, 4, 16), 256, 0, stream>>>(x, W, uT, vT);
        stats_kernel<<<dim3(32, 16), 256, 0, stream>>>(uT, vT, idx, gsum);
        finalize_kernel<<<1, 256, 0, stream>>>(gsum, gamma, beta, st);
        out_kernel<<<dim3(32, 16), 256, 0, stream>>>(uT, vT, idx, st, out);
    }
}